// Round 1
// baseline (17559.871 us; speedup 1.0000x reference)
//
#include <hip/hip_runtime.h>
#include <math.h>

#define BBATCH 32
#define NTOK 197
#define NPATCH 196
#define PDIM 768
#define DDIM 512
#define NHEAD 8
#define DHEAD 64
#define MLPDIM 2048
#define NLAYER 10
#define NCLASS 10
#define MTOK (BBATCH*NTOK)      // 6304
#define MPATCH (BBATCH*NPATCH)  // 6272

__device__ __forceinline__ float gelu_f(float x) {
    return 0.5f * x * (1.0f + erff(x * 0.70710678118654752440f));
}

// ---------------------------------------------------------------------------
// Generic tiled GEMM: Cout[M,N] = (res? res : 0) + act(A[M,K] @ W[N,K]^T + bias)
// 64x64 tile, 256 threads, 4x4 micro-tile per thread.
// ---------------------------------------------------------------------------
template<int ACT, bool HASB, bool HASR>
__global__ __launch_bounds__(256)
void gemm_kernel(const float* __restrict__ A, const float* __restrict__ W,
                 const float* __restrict__ bias, const float* __restrict__ res,
                 float* __restrict__ Cout, int M, int Nn, int K)
{
    __shared__ float As[16][64];
    __shared__ float Bs[16][64];
    const int tid = threadIdx.x;
    const int tx = tid & 15, ty = tid >> 4;
    const int m0 = blockIdx.y * 64, n0 = blockIdx.x * 64;
    float acc[4][4] = {};
    for (int k0 = 0; k0 < K; k0 += 16) {
        #pragma unroll
        for (int i = 0; i < 4; i++) {
            int e = tid + i * 256;          // 0..1023
            int r = e >> 4, c = e & 15;
            int gm = m0 + r, gn = n0 + r, gk = k0 + c;
            As[c][r] = (gm < M)  ? A[(size_t)gm * K + gk] : 0.0f;
            Bs[c][r] = (gn < Nn) ? W[(size_t)gn * K + gk] : 0.0f;
        }
        __syncthreads();
        #pragma unroll
        for (int kk = 0; kk < 16; kk++) {
            float av[4], bv[4];
            #pragma unroll
            for (int i = 0; i < 4; i++) av[i] = As[kk][ty * 4 + i];
            #pragma unroll
            for (int j = 0; j < 4; j++) bv[j] = Bs[kk][tx * 4 + j];
            #pragma unroll
            for (int i = 0; i < 4; i++)
                #pragma unroll
                for (int j = 0; j < 4; j++)
                    acc[i][j] = fmaf(av[i], bv[j], acc[i][j]);
        }
        __syncthreads();
    }
    #pragma unroll
    for (int i = 0; i < 4; i++) {
        int gm = m0 + ty * 4 + i;
        if (gm >= M) continue;
        #pragma unroll
        for (int j = 0; j < 4; j++) {
            int gn = n0 + tx * 4 + j;
            if (gn >= Nn) continue;
            float v = acc[i][j];
            if (HASB) v += bias[gn];
            if (ACT == 1) v = gelu_f(v);
            if (HASR) v += res[(size_t)gm * Nn + gn];
            Cout[(size_t)gm * Nn + gn] = v;
        }
    }
}

// ---------------------------------------------------------------------------
// LayerNorm over rows of length 512: one wave (64 lanes) per row.
// ---------------------------------------------------------------------------
__global__ __launch_bounds__(256)
void ln_kernel(const float* __restrict__ X, const float* __restrict__ g,
               const float* __restrict__ bb, float* __restrict__ Y, int M)
{
    int wave = (blockIdx.x * 4) + (threadIdx.x >> 6);
    int lane = threadIdx.x & 63;
    if (wave >= M) return;
    const float* x = X + (size_t)wave * DDIM;
    float v[8];
    float s = 0.0f;
    #pragma unroll
    for (int i = 0; i < 8; i++) { v[i] = x[lane + i * 64]; s += v[i]; }
    #pragma unroll
    for (int off = 32; off; off >>= 1) s += __shfl_xor(s, off, 64);
    float mu = s * (1.0f / 512.0f);
    float q = 0.0f;
    #pragma unroll
    for (int i = 0; i < 8; i++) { float d = v[i] - mu; q += d * d; }
    #pragma unroll
    for (int off = 32; off; off >>= 1) q += __shfl_xor(q, off, 64);
    float inv = 1.0f / sqrtf(q * (1.0f / 512.0f) + 1e-5f);
    float* y = Y + (size_t)wave * DDIM;
    #pragma unroll
    for (int i = 0; i < 8; i++) {
        int c = lane + i * 64;
        y[c] = (v[i] - mu) * inv * g[c] + bb[c];
    }
}

// ---------------------------------------------------------------------------
// Patch extraction: xp[b][n][pd], pd = (py*16+px)*3 + c
// ---------------------------------------------------------------------------
__global__ __launch_bounds__(256)
void patch_kernel(const float* __restrict__ x, float* __restrict__ xp)
{
    size_t idx = (size_t)blockIdx.x * 256 + threadIdx.x;
    if (idx >= (size_t)MPATCH * PDIM) return;
    int pd = (int)(idx % PDIM);
    int bn = (int)(idx / PDIM);
    int n = bn % NPATCH, b = bn / NPATCH;
    int c = pd % 3, pix = pd / 3;
    int px = pix % 16, py = pix / 16;
    int hx = n % 14, hy = n / 14;
    int row = hy * 16 + py, col = hx * 16 + px;
    xp[idx] = x[((size_t)(b * 3 + c) * 224 + row) * 224 + col];
}

// z = concat(cls_tok, e) + pos_emb
__global__ __launch_bounds__(256)
void assemble_kernel(const float* __restrict__ e, const float* __restrict__ clstok,
                     const float* __restrict__ pos, float* __restrict__ U)
{
    size_t idx = (size_t)blockIdx.x * 256 + threadIdx.x;
    if (idx >= (size_t)MTOK * DDIM) return;
    int d = (int)(idx % DDIM);
    int bt = (int)(idx / DDIM);
    int t = bt % NTOK, b = bt / NTOK;
    float v = (t == 0) ? clstok[d] : e[((size_t)b * NPATCH + (t - 1)) * DDIM + d];
    U[idx] = v + pos[t * DDIM + d];
}

// ---------------------------------------------------------------------------
// Attention: one block (256 thr = 4 waves) per (b, h). K and V staged in LDS
// with pad-65 stride (conflict-free). Each wave owns rows i = wv, wv+4, ...
// ---------------------------------------------------------------------------
__global__ __launch_bounds__(256)
void attn_kernel(const float* __restrict__ qkv, float* __restrict__ O)
{
    int b = blockIdx.x >> 3, h = blockIdx.x & 7;
    __shared__ float Ks[NTOK][DHEAD + 1];
    __shared__ float Vs[NTOK][DHEAD + 1];
    __shared__ float sc[4][NTOK];
    const int tid = threadIdx.x;
    const size_t base = (size_t)b * NTOK * 1536 + h * DHEAD;
    for (int e = tid; e < NTOK * DHEAD; e += 256) {
        int j = e >> 6, d = e & 63;
        Ks[j][d] = qkv[base + (size_t)j * 1536 + 512 + d];
        Vs[j][d] = qkv[base + (size_t)j * 1536 + 1024 + d];
    }
    __syncthreads();
    const int wv = tid >> 6, lane = tid & 63;
    const float scale = 0.04419417382415922f;  // 1/sqrt(512)
    for (int i = wv; i < NTOK; i += 4) {
        float qv = qkv[base + (size_t)i * 1536 + lane];
        float a0 = 0.f, a1 = 0.f, a2 = 0.f, a3 = 0.f;
        const int j0 = lane, j1 = lane + 64, j2 = lane + 128, j3 = lane + 192;
        const int j3s = (j3 < NTOK) ? j3 : 0;
        #pragma unroll 16
        for (int d = 0; d < 64; d++) {
            float qd = __shfl(qv, d, 64);
            a0 = fmaf(qd, Ks[j0][d], a0);
            a1 = fmaf(qd, Ks[j1][d], a1);
            a2 = fmaf(qd, Ks[j2][d], a2);
            a3 = fmaf(qd, Ks[j3s][d], a3);
        }
        a0 *= scale; a1 *= scale; a2 *= scale; a3 *= scale;
        const bool v3 = (j3 < NTOK);
        float mx = fmaxf(fmaxf(a0, a1), fmaxf(a2, v3 ? a3 : -INFINITY));
        #pragma unroll
        for (int off = 32; off; off >>= 1) mx = fmaxf(mx, __shfl_xor(mx, off, 64));
        float e0 = expf(a0 - mx), e1 = expf(a1 - mx), e2 = expf(a2 - mx);
        float e3 = v3 ? expf(a3 - mx) : 0.0f;
        float s = e0 + e1 + e2 + e3;
        #pragma unroll
        for (int off = 32; off; off >>= 1) s += __shfl_xor(s, off, 64);
        float inv = 1.0f / s;
        sc[wv][j0] = e0 * inv;
        sc[wv][j1] = e1 * inv;
        sc[wv][j2] = e2 * inv;
        if (v3) sc[wv][j3] = e3 * inv;
        float o = 0.0f;
        for (int j = 0; j < NTOK; j++) o = fmaf(sc[wv][j], Vs[j][lane], o);
        O[((size_t)b * NTOK + i) * DDIM + h * DHEAD + lane] = o;
    }
}

// halt score per token: sigmoid(hh . Wh2 + bh2). One wave per token.
__global__ __launch_bounds__(256)
void halt_dot_kernel(const float* __restrict__ Hh, const float* __restrict__ Wh2,
                     const float* __restrict__ bh2, float* __restrict__ hsc)
{
    int wave = (blockIdx.x * 4) + (threadIdx.x >> 6);
    int lane = threadIdx.x & 63;
    if (wave >= MTOK) return;
    const float* row = Hh + (size_t)wave * MLPDIM;
    float s = 0.0f;
    #pragma unroll
    for (int i = 0; i < MLPDIM / 64; i++) s = fmaf(row[lane + i * 64], Wh2[lane + i * 64], s);
    #pragma unroll
    for (int off = 32; off; off >>= 1) s += __shfl_xor(s, off, 64);
    if (lane == 0) hsc[wave] = 1.0f / (1.0f + expf(-(s + bh2[0])));
}

// halts[b][l] = mean_t hsc;  cls[b][l][:] = U[b*197+0][:]
__global__ __launch_bounds__(64)
void halt_mean_cls_kernel(const float* __restrict__ hsc, const float* __restrict__ U,
                          float* __restrict__ halts, float* __restrict__ cls, int l)
{
    int b = blockIdx.x, lane = threadIdx.x;
    float s = 0.0f;
    for (int t = lane; t < NTOK; t += 64) s += hsc[b * NTOK + t];
    #pragma unroll
    for (int off = 32; off; off >>= 1) s += __shfl_xor(s, off, 64);
    if (lane == 0) halts[b * NLAYER + l] = s * (1.0f / (float)NTOK);
    for (int d = lane; d < DDIM; d += 64)
        cls[((size_t)b * NLAYER + l) * DDIM + d] = U[(size_t)b * NTOK * DDIM + d];
}

// ce[b*L+l] = -log_softmax(logits)[y[b]]
__global__ __launch_bounds__(256)
void ce_kernel(const float* __restrict__ logits, const int* __restrict__ y,
               float* __restrict__ ce)
{
    int r = blockIdx.x * 256 + threadIdx.x;
    if (r >= BBATCH * NLAYER) return;
    const float* lg = logits + (size_t)r * NCLASS;
    float mx = lg[0];
    #pragma unroll
    for (int i = 1; i < NCLASS; i++) mx = fmaxf(mx, lg[i]);
    float s = 0.0f;
    #pragma unroll
    for (int i = 0; i < NCLASS; i++) s += expf(lg[i] - mx);
    int lab = y[r / NLAYER];
    ce[r] = -(lg[lab] - mx - logf(s));
}

// final ACT loss reduction
__global__ __launch_bounds__(64)
void loss_kernel(const float* __restrict__ ce, const float* __restrict__ halts,
                 float* __restrict__ out)
{
    int b = threadIdx.x;
    float total = 0.0f;
    if (b < BBATCH) {
        const float* c = ce + b * NLAYER;
        int idx = 0; float mn = c[0];
        for (int l = 1; l < NLAYER; l++) if (c[l] < mn) { mn = c[l]; idx = l; }
        idx += 1;
        float acc = 0.0f;
        for (int l = 0; l < idx; l++) {
            acc += c[l];
            float p = halts[b * NLAYER + l];
            p = fminf(fmaxf(p, 1e-7f), 1.0f - 1e-7f);
            float hl = (l == idx - 1) ? 0.0f : 1.0f;
            acc += -(hl * logf(p) + (1.0f - hl) * log1pf(-p));
        }
        total = acc / (float)idx;
    }
    #pragma unroll
    for (int off = 32; off; off >>= 1) total += __shfl_xor(total, off, 64);
    if (threadIdx.x == 0) out[0] = total * (1.0f / (float)BBATCH);
}

extern "C" void kernel_launch(void* const* d_in, const int* in_sizes, int n_in,
                              void* d_out, int out_size, void* d_ws, size_t ws_size,
                              hipStream_t stream)
{
    const float* x      = (const float*)d_in[0];
    const int*   y      = (const int*)d_in[1];
    const float* pos    = (const float*)d_in[2];
    const float* clstok = (const float*)d_in[3];
    const float* Wp     = (const float*)d_in[4];
    const float* bp     = (const float*)d_in[5];
    const float* Wqkv   = (const float*)d_in[6];
    const float* Wo     = (const float*)d_in[7];
    const float* bo     = (const float*)d_in[8];
    const float* ln1g   = (const float*)d_in[9];
    const float* ln1b   = (const float*)d_in[10];
    const float* ln2g   = (const float*)d_in[11];
    const float* ln2b   = (const float*)d_in[12];
    const float* W1     = (const float*)d_in[13];
    const float* b1     = (const float*)d_in[14];
    const float* W2     = (const float*)d_in[15];
    const float* b2     = (const float*)d_in[16];
    const float* lnhg   = (const float*)d_in[17];
    const float* lnhb   = (const float*)d_in[18];
    const float* Wh1    = (const float*)d_in[19];
    const float* bh1    = (const float*)d_in[20];
    const float* Wh2    = (const float*)d_in[21];
    const float* bh2    = (const float*)d_in[22];
    const float* lncg   = (const float*)d_in[23];
    const float* lncb   = (const float*)d_in[24];
    const float* Wc1    = (const float*)d_in[25];
    const float* bc1    = (const float*)d_in[26];
    const float* Wc2    = (const float*)d_in[27];
    const float* bc2    = (const float*)d_in[28];

    float* ws     = (float*)d_ws;
    float* U      = ws;                               // MTOK*512
    float* LNB    = U     + (size_t)MTOK * DDIM;      // MTOK*512 (ln out, attn out, cls-ln)
    float* QKV    = LNB   + (size_t)MTOK * DDIM;      // MTOK*1536 (also xp)
    float* HB     = QKV   + (size_t)MTOK * 1536;      // MTOK*2048 (also e, mlp/halt/head hidden)
    float* HSC    = HB    + (size_t)MTOK * MLPDIM;    // MTOK
    float* HALTS  = HSC   + MTOK;                     // 320
    float* CLS    = HALTS + BBATCH * NLAYER;          // 320*512
    float* LOGITS = CLS   + (size_t)BBATCH * NLAYER * DDIM;  // 3200
    float* CE     = LOGITS + BBATCH * NLAYER * NCLASS;       // 320

    dim3 blk(256);

    // patch embed: xp (in QKV buf) -> e (in HB buf) -> assemble U
    patch_kernel<<<dim3(((size_t)MPATCH * PDIM + 255) / 256), blk, 0, stream>>>(x, QKV);
    gemm_kernel<0, true, false><<<dim3(DDIM / 64, (MPATCH + 63) / 64), blk, 0, stream>>>(
        QKV, Wp, bp, nullptr, HB, MPATCH, DDIM, PDIM);
    assemble_kernel<<<dim3(((size_t)MTOK * DDIM + 255) / 256), blk, 0, stream>>>(
        HB, clstok, pos, U);

    for (int l = 0; l < NLAYER; l++) {
        ln_kernel<<<dim3((MTOK + 3) / 4), blk, 0, stream>>>(U, ln1g, ln1b, LNB, MTOK);
        gemm_kernel<0, false, false><<<dim3(1536 / 64, (MTOK + 63) / 64), blk, 0, stream>>>(
            LNB, Wqkv, nullptr, nullptr, QKV, MTOK, 1536, DDIM);
        attn_kernel<<<dim3(BBATCH * NHEAD), blk, 0, stream>>>(QKV, LNB);
        gemm_kernel<0, true, true><<<dim3(DDIM / 64, (MTOK + 63) / 64), blk, 0, stream>>>(
            LNB, Wo, bo, U, U, MTOK, DDIM, DDIM);
        ln_kernel<<<dim3((MTOK + 3) / 4), blk, 0, stream>>>(U, ln2g, ln2b, LNB, MTOK);
        gemm_kernel<1, true, false><<<dim3(MLPDIM / 64, (MTOK + 63) / 64), blk, 0, stream>>>(
            LNB, W1, b1, nullptr, HB, MTOK, MLPDIM, DDIM);
        gemm_kernel<0, true, true><<<dim3(DDIM / 64, (MTOK + 63) / 64), blk, 0, stream>>>(
            HB, W2, b2, U, U, MTOK, DDIM, MLPDIM);
        ln_kernel<<<dim3((MTOK + 3) / 4), blk, 0, stream>>>(U, lnhg, lnhb, LNB, MTOK);
        gemm_kernel<1, true, false><<<dim3(MLPDIM / 64, (MTOK + 63) / 64), blk, 0, stream>>>(
            LNB, Wh1, bh1, nullptr, HB, MTOK, MLPDIM, DDIM);
        halt_dot_kernel<<<dim3((MTOK + 3) / 4), blk, 0, stream>>>(HB, Wh2, bh2, HSC);
        halt_mean_cls_kernel<<<dim3(BBATCH), dim3(64), 0, stream>>>(HSC, U, HALTS, CLS, l);
    }

    // head
    ln_kernel<<<dim3((BBATCH * NLAYER + 3) / 4), blk, 0, stream>>>(
        CLS, lncg, lncb, LNB, BBATCH * NLAYER);
    gemm_kernel<1, true, false><<<dim3(MLPDIM / 64, (BBATCH * NLAYER + 63) / 64), blk, 0, stream>>>(
        LNB, Wc1, bc1, nullptr, HB, BBATCH * NLAYER, MLPDIM, DDIM);
    gemm_kernel<0, true, false><<<dim3(1, (BBATCH * NLAYER + 63) / 64), blk, 0, stream>>>(
        HB, Wc2, bc2, nullptr, LOGITS, BBATCH * NLAYER, NCLASS, MLPDIM);
    ce_kernel<<<dim3(2), blk, 0, stream>>>(LOGITS, y, CE);
    loss_kernel<<<dim3(1), dim3(64), 0, stream>>>(CE, HALTS, (float*)d_out);
}

// Round 2
// 5317.110 us; speedup vs baseline: 3.3025x; 3.3025x over previous
//
#include <hip/hip_runtime.h>
#include <math.h>

#define BBATCH 32
#define NTOK 197
#define NPATCH 196
#define PDIM 768
#define DDIM 512
#define NHEAD 8
#define DHEAD 64
#define MLPDIM 2048
#define NLAYER 10
#define NCLASS 10
#define MTOK (BBATCH*NTOK)      // 6304
#define MPAD 6400               // padded rows for MFMA A-tiles (50*128)
#define MPATCH (BBATCH*NPATCH)  // 6272

typedef unsigned short u16;
typedef __attribute__((ext_vector_type(8))) short bf16x8;
typedef __attribute__((ext_vector_type(4))) float f32x4;
typedef __attribute__((ext_vector_type(8))) unsigned short ushort8;

__device__ __forceinline__ float gelu_f(float x) {
    return 0.5f * x * (1.0f + erff(x * 0.70710678118654752440f));
}
__device__ __forceinline__ float bf2f(u16 u) {
    union { unsigned int i; float f; } v; v.i = ((unsigned int)u) << 16; return v.f;
}
__device__ __forceinline__ u16 f2bf(float f) {
    union { float f; unsigned int u; } v; v.f = f;
    unsigned int r = v.u + 0x7FFFu + ((v.u >> 16) & 1u);
    return (u16)(r >> 16);
}
__device__ __forceinline__ void gload_lds16(const u16* g, u16* l) {
    __builtin_amdgcn_global_load_lds((const __attribute__((address_space(1))) void*)g,
                                     (__attribute__((address_space(3))) void*)l, 16, 0, 0);
}

// ---------------------------------------------------------------------------
// bf16 MFMA GEMM: C[M,N] = (res?) + act(A[M,K](bf16) @ W[N,K](bf16)^T + bias)
// 128x128 tile, BK=64, 256 thr = 4 waves (2x2), 64x64 per wave.
// LDS: linear [128][64] bf16 dest for global_load_lds; T2 XOR swizzle done by
// pre-swizzling the GLOBAL source column and swizzling the ds_read address
// (rule #21: both-sides-or-neither). byte ^= ((row&7)<<4).
// ---------------------------------------------------------------------------
template<int ACT, int HASB, int HASR, int OUTBF>
__global__ __launch_bounds__(256)
void mgemm_kernel(const u16* __restrict__ A, const u16* __restrict__ W,
                  const float* __restrict__ bias, const float* __restrict__ res,
                  void* __restrict__ Cout, int M, int Nn, int K)
{
    __shared__ u16 As[128 * 64];
    __shared__ u16 Bs[128 * 64];
    const int tid = threadIdx.x;
    const int lane = tid & 63;
    const int wid = tid >> 6;
    const int wr = wid >> 1, wc = wid & 1;
    const int m0 = blockIdx.y * 128, n0 = blockIdx.x * 128;

    f32x4 acc[4][4] = {};

    const int srow = tid >> 3;          // 0..31 (row within 32-row pass)
    const int dcb  = (tid & 7) << 4;    // dest byte col within 128B row

    for (int k0 = 0; k0 < K; k0 += 64) {
        __syncthreads();
        #pragma unroll
        for (int p = 0; p < 4; ++p) {
            int r = p * 32 + srow;
            int scb = dcb ^ ((r & 7) << 4);   // inverse-swizzled source col (bytes)
            gload_lds16(A + (size_t)(m0 + r) * K + k0 + (scb >> 1), &As[p * 2048 + tid * 8]);
            gload_lds16(W + (size_t)(n0 + r) * K + k0 + (scb >> 1), &Bs[p * 2048 + tid * 8]);
        }
        __syncthreads();

        #pragma unroll
        for (int kk = 0; kk < 64; kk += 32) {
            const int kb = (kk + ((lane >> 4) << 3)) << 1;  // byte col pre-swizzle
            bf16x8 af[4], bfr[4];
            #pragma unroll
            for (int mi = 0; mi < 4; ++mi) {
                int ar = wr * 64 + mi * 16 + (lane & 15);
                af[mi] = *(const bf16x8*)&As[ar * 64 + ((kb ^ ((ar & 7) << 4)) >> 1)];
            }
            #pragma unroll
            for (int ni = 0; ni < 4; ++ni) {
                int br = wc * 64 + ni * 16 + (lane & 15);
                bfr[ni] = *(const bf16x8*)&Bs[br * 64 + ((kb ^ ((br & 7) << 4)) >> 1)];
            }
            #pragma unroll
            for (int mi = 0; mi < 4; ++mi)
                #pragma unroll
                for (int ni = 0; ni < 4; ++ni)
                    acc[mi][ni] = __builtin_amdgcn_mfma_f32_16x16x32_bf16(
                        af[mi], bfr[ni], acc[mi][ni], 0, 0, 0);
        }
    }

    float* outf = (float*)Cout;
    u16*   outb = (u16*)Cout;
    #pragma unroll
    for (int mi = 0; mi < 4; ++mi) {
        #pragma unroll
        for (int j = 0; j < 4; ++j) {
            int row = m0 + wr * 64 + mi * 16 + ((lane >> 4) << 2) + j;
            if (row >= M) continue;
            #pragma unroll
            for (int ni = 0; ni < 4; ++ni) {
                int col = n0 + wc * 64 + ni * 16 + (lane & 15);
                float v = acc[mi][ni][j];
                if (HASB) v += bias[col];
                if (ACT)  v = gelu_f(v);
                if (HASR) v += res[(size_t)row * Nn + col];
                if (OUTBF) outb[(size_t)row * Nn + col] = f2bf(v);
                else       outf[(size_t)row * Nn + col] = v;
            }
        }
    }
}

// fp32 -> bf16 bulk convert (n divisible by 4)
__global__ __launch_bounds__(256)
void f2bf_kernel(const float* __restrict__ in, u16* __restrict__ out, int n4)
{
    int i = blockIdx.x * 256 + threadIdx.x;
    if (i >= n4) return;
    float4 v = ((const float4*)in)[i];
    u16 o0 = f2bf(v.x), o1 = f2bf(v.y), o2 = f2bf(v.z), o3 = f2bf(v.w);
    out[i * 4 + 0] = o0; out[i * 4 + 1] = o1; out[i * 4 + 2] = o2; out[i * 4 + 3] = o3;
}

// ---------------------------------------------------------------------------
// LayerNorm rows of 512: one wave per row; fp32 in, bf16 out.
// ---------------------------------------------------------------------------
__global__ __launch_bounds__(256)
void ln_kernel(const float* __restrict__ X, const float* __restrict__ g,
               const float* __restrict__ bb, u16* __restrict__ Y, int M)
{
    int wave = (blockIdx.x * 4) + (threadIdx.x >> 6);
    int lane = threadIdx.x & 63;
    if (wave >= M) return;
    const float* x = X + (size_t)wave * DDIM;
    float v[8];
    float s = 0.0f;
    #pragma unroll
    for (int i = 0; i < 8; i++) { v[i] = x[lane + i * 64]; s += v[i]; }
    #pragma unroll
    for (int off = 32; off; off >>= 1) s += __shfl_xor(s, off, 64);
    float mu = s * (1.0f / 512.0f);
    float q = 0.0f;
    #pragma unroll
    for (int i = 0; i < 8; i++) { float d = v[i] - mu; q += d * d; }
    #pragma unroll
    for (int off = 32; off; off >>= 1) q += __shfl_xor(q, off, 64);
    float inv = 1.0f / sqrtf(q * (1.0f / 512.0f) + 1e-5f);
    u16* y = Y + (size_t)wave * DDIM;
    #pragma unroll
    for (int i = 0; i < 8; i++) {
        int c = lane + i * 64;
        y[c] = f2bf((v[i] - mu) * inv * g[c] + bb[c]);
    }
}

// ---------------------------------------------------------------------------
// Patch extraction -> bf16
// ---------------------------------------------------------------------------
__global__ __launch_bounds__(256)
void patch_kernel(const float* __restrict__ x, u16* __restrict__ xp)
{
    size_t idx = (size_t)blockIdx.x * 256 + threadIdx.x;
    if (idx >= (size_t)MPATCH * PDIM) return;
    int pd = (int)(idx % PDIM);
    int bn = (int)(idx / PDIM);
    int n = bn % NPATCH, b = bn / NPATCH;
    int c = pd % 3, pix = pd / 3;
    int px = pix % 16, py = pix / 16;
    int hx = n % 14, hy = n / 14;
    int row = hy * 16 + py, col = hx * 16 + px;
    xp[idx] = f2bf(x[((size_t)(b * 3 + c) * 224 + row) * 224 + col]);
}

// z = concat(cls_tok, e) + pos_emb (all fp32)
__global__ __launch_bounds__(256)
void assemble_kernel(const float* __restrict__ e, const float* __restrict__ clstok,
                     const float* __restrict__ pos, float* __restrict__ U)
{
    size_t idx = (size_t)blockIdx.x * 256 + threadIdx.x;
    if (idx >= (size_t)MTOK * DDIM) return;
    int d = (int)(idx % DDIM);
    int bt = (int)(idx / DDIM);
    int t = bt % NTOK, b = bt / NTOK;
    float v = (t == 0) ? clstok[d] : e[((size_t)b * NPATCH + (t - 1)) * DDIM + d];
    U[idx] = v + pos[t * DDIM + d];
}

// ---------------------------------------------------------------------------
// Attention (fp32 VALU): one block per (b,h); K,V staged in LDS stride-65.
// Output written bf16 (feeds Wo MFMA GEMM).
// ---------------------------------------------------------------------------
__global__ __launch_bounds__(256)
void attn_kernel(const float* __restrict__ qkv, u16* __restrict__ O)
{
    int b = blockIdx.x >> 3, h = blockIdx.x & 7;
    __shared__ float Ks[NTOK][DHEAD + 1];
    __shared__ float Vs[NTOK][DHEAD + 1];
    __shared__ float sc[4][NTOK];
    const int tid = threadIdx.x;
    const size_t base = (size_t)b * NTOK * 1536 + h * DHEAD;
    for (int e = tid; e < NTOK * DHEAD; e += 256) {
        int j = e >> 6, d = e & 63;
        Ks[j][d] = qkv[base + (size_t)j * 1536 + 512 + d];
        Vs[j][d] = qkv[base + (size_t)j * 1536 + 1024 + d];
    }
    __syncthreads();
    const int wv = tid >> 6, lane = tid & 63;
    const float scale = 0.04419417382415922f;  // 1/sqrt(512)
    for (int i = wv; i < NTOK; i += 4) {
        float qv = qkv[base + (size_t)i * 1536 + lane];
        float a0 = 0.f, a1 = 0.f, a2 = 0.f, a3 = 0.f;
        const int j0 = lane, j1 = lane + 64, j2 = lane + 128, j3 = lane + 192;
        const int j3s = (j3 < NTOK) ? j3 : 0;
        #pragma unroll 16
        for (int d = 0; d < 64; d++) {
            float qd = __shfl(qv, d, 64);
            a0 = fmaf(qd, Ks[j0][d], a0);
            a1 = fmaf(qd, Ks[j1][d], a1);
            a2 = fmaf(qd, Ks[j2][d], a2);
            a3 = fmaf(qd, Ks[j3s][d], a3);
        }
        a0 *= scale; a1 *= scale; a2 *= scale; a3 *= scale;
        const bool v3 = (j3 < NTOK);
        float mx = fmaxf(fmaxf(a0, a1), fmaxf(a2, v3 ? a3 : -INFINITY));
        #pragma unroll
        for (int off = 32; off; off >>= 1) mx = fmaxf(mx, __shfl_xor(mx, off, 64));
        float e0 = expf(a0 - mx), e1 = expf(a1 - mx), e2 = expf(a2 - mx);
        float e3 = v3 ? expf(a3 - mx) : 0.0f;
        float s = e0 + e1 + e2 + e3;
        #pragma unroll
        for (int off = 32; off; off >>= 1) s += __shfl_xor(s, off, 64);
        float inv = 1.0f / s;
        sc[wv][j0] = e0 * inv;
        sc[wv][j1] = e1 * inv;
        sc[wv][j2] = e2 * inv;
        if (v3) sc[wv][j3] = e3 * inv;
        float o = 0.0f;
        for (int j = 0; j < NTOK; j++) o = fmaf(sc[wv][j], Vs[j][lane], o);
        O[((size_t)b * NTOK + i) * DDIM + h * DHEAD + lane] = f2bf(o);
    }
}

// halt score per token: sigmoid(hh . Wh2 + bh2). One wave per token, bf16 A.
__global__ __launch_bounds__(256)
void halt_dot_kernel(const u16* __restrict__ Hh, const float* __restrict__ Wh2,
                     const float* __restrict__ bh2, float* __restrict__ hsc)
{
    int wave = (blockIdx.x * 4) + (threadIdx.x >> 6);
    int lane = threadIdx.x & 63;
    if (wave >= MTOK) return;
    const u16* row = Hh + (size_t)wave * MLPDIM;
    float s = 0.0f;
    #pragma unroll
    for (int i = 0; i < 4; i++) {
        ushort8 v = *(const ushort8*)&row[i * 512 + lane * 8];
        #pragma unroll
        for (int j = 0; j < 8; j++)
            s = fmaf(bf2f(v[j]), Wh2[i * 512 + lane * 8 + j], s);
    }
    #pragma unroll
    for (int off = 32; off; off >>= 1) s += __shfl_xor(s, off, 64);
    if (lane == 0) hsc[wave] = 1.0f / (1.0f + expf(-(s + bh2[0])));
}

// halts[b][l] = mean_t hsc;  cls[b][l][:] = U[b*197+0][:]
__global__ __launch_bounds__(64)
void halt_mean_cls_kernel(const float* __restrict__ hsc, const float* __restrict__ U,
                          float* __restrict__ halts, float* __restrict__ cls, int l)
{
    int b = blockIdx.x, lane = threadIdx.x;
    float s = 0.0f;
    for (int t = lane; t < NTOK; t += 64) s += hsc[b * NTOK + t];
    #pragma unroll
    for (int off = 32; off; off >>= 1) s += __shfl_xor(s, off, 64);
    if (lane == 0) halts[b * NLAYER + l] = s * (1.0f / (float)NTOK);
    for (int d = lane; d < DDIM; d += 64)
        cls[((size_t)b * NLAYER + l) * DDIM + d] = U[(size_t)b * NTOK * DDIM + d];
}

// head logits: one wave per (b,l) row; 10 dots of length 2048 (A bf16, W fp32)
__global__ __launch_bounds__(256)
void head_logits_kernel(const u16* __restrict__ Hh, const float* __restrict__ Wc2,
                        const float* __restrict__ bc2, float* __restrict__ logits)
{
    int wave = (blockIdx.x * 4) + (threadIdx.x >> 6);
    int lane = threadIdx.x & 63;
    if (wave >= BBATCH * NLAYER) return;
    const u16* row = Hh + (size_t)wave * MLPDIM;
    float rv[32];
    #pragma unroll
    for (int i = 0; i < 32; i++) rv[i] = bf2f(row[lane + i * 64]);
    #pragma unroll
    for (int c = 0; c < NCLASS; c++) {
        float s = 0.0f;
        #pragma unroll
        for (int i = 0; i < 32; i++) s = fmaf(rv[i], Wc2[c * MLPDIM + lane + i * 64], s);
        #pragma unroll
        for (int off = 32; off; off >>= 1) s += __shfl_xor(s, off, 64);
        if (lane == 0) logits[wave * NCLASS + c] = s + bc2[c];
    }
}

// ce[b*L+l] = -log_softmax(logits)[y[b]]
__global__ __launch_bounds__(256)
void ce_kernel(const float* __restrict__ logits, const int* __restrict__ y,
               float* __restrict__ ce)
{
    int r = blockIdx.x * 256 + threadIdx.x;
    if (r >= BBATCH * NLAYER) return;
    const float* lg = logits + (size_t)r * NCLASS;
    float mx = lg[0];
    #pragma unroll
    for (int i = 1; i < NCLASS; i++) mx = fmaxf(mx, lg[i]);
    float s = 0.0f;
    #pragma unroll
    for (int i = 0; i < NCLASS; i++) s += expf(lg[i] - mx);
    int lab = y[r / NLAYER];
    ce[r] = -(lg[lab] - mx - logf(s));
}

// final ACT loss reduction
__global__ __launch_bounds__(64)
void loss_kernel(const float* __restrict__ ce, const float* __restrict__ halts,
                 float* __restrict__ out)
{
    int b = threadIdx.x;
    float total = 0.0f;
    if (b < BBATCH) {
        const float* c = ce + b * NLAYER;
        int idx = 0; float mn = c[0];
        for (int l = 1; l < NLAYER; l++) if (c[l] < mn) { mn = c[l]; idx = l; }
        idx += 1;
        float acc = 0.0f;
        for (int l = 0; l < idx; l++) {
            acc += c[l];
            float p = halts[b * NLAYER + l];
            p = fminf(fmaxf(p, 1e-7f), 1.0f - 1e-7f);
            float hl = (l == idx - 1) ? 0.0f : 1.0f;
            acc += -(hl * logf(p) + (1.0f - hl) * log1pf(-p));
        }
        total = acc / (float)idx;
    }
    #pragma unroll
    for (int off = 32; off; off >>= 1) total += __shfl_xor(total, off, 64);
    if (threadIdx.x == 0) out[0] = total * (1.0f / (float)BBATCH);
}

extern "C" void kernel_launch(void* const* d_in, const int* in_sizes, int n_in,
                              void* d_out, int out_size, void* d_ws, size_t ws_size,
                              hipStream_t stream)
{
    const float* x      = (const float*)d_in[0];
    const int*   y      = (const int*)d_in[1];
    const float* pos    = (const float*)d_in[2];
    const float* clstok = (const float*)d_in[3];
    const float* Wp     = (const float*)d_in[4];
    const float* bp     = (const float*)d_in[5];
    const float* Wqkv   = (const float*)d_in[6];
    const float* Wo     = (const float*)d_in[7];
    const float* bo     = (const float*)d_in[8];
    const float* ln1g   = (const float*)d_in[9];
    const float* ln1b   = (const float*)d_in[10];
    const float* ln2g   = (const float*)d_in[11];
    const float* ln2b   = (const float*)d_in[12];
    const float* W1     = (const float*)d_in[13];
    const float* b1     = (const float*)d_in[14];
    const float* W2     = (const float*)d_in[15];
    const float* b2     = (const float*)d_in[16];
    const float* lnhg   = (const float*)d_in[17];
    const float* lnhb   = (const float*)d_in[18];
    const float* Wh1    = (const float*)d_in[19];
    const float* bh1    = (const float*)d_in[20];
    const float* Wh2    = (const float*)d_in[21];
    const float* bh2    = (const float*)d_in[22];
    const float* lncg   = (const float*)d_in[23];
    const float* lncb   = (const float*)d_in[24];
    const float* Wc1    = (const float*)d_in[25];
    const float* bc1    = (const float*)d_in[26];
    const float* Wc2    = (const float*)d_in[27];
    const float* bc2    = (const float*)d_in[28];

    // ---- workspace layout ----
    float* U      = (float*)d_ws;                    // MTOK*512
    float* QKV    = U + (size_t)MTOK * DDIM;         // MTOK*1536 (also patch-embed E)
    float* CLS    = QKV + (size_t)MTOK * 1536;       // 320*512
    float* LOGITS = CLS + (size_t)BBATCH * NLAYER * DDIM;   // 3200
    float* CE     = LOGITS + BBATCH * NLAYER * NCLASS;      // 320
    float* HSC    = CE + BBATCH * NLAYER;            // MTOK
    float* HALTS  = HSC + MTOK;                      // 320
    u16* LNB  = (u16*)(HALTS + BBATCH * NLAYER);     // MPAD*512 (ln out / attn out)
    u16* HB   = LNB + (size_t)MPAD * DDIM;           // MPAD*2048 (mlp/halt hidden)
    u16* XP   = HB + (size_t)MPAD * MLPDIM;          // 6272*768
    u16* CLNB = XP + (size_t)MPATCH * PDIM;          // 384*512 (head-ln out, padded)
    u16* wWp  = CLNB + 384 * DDIM;                   // 512*768
    u16* wWqkv= wWp   + 512 * 768;                   // 1536*512
    u16* wWo  = wWqkv + 1536 * 512;                  // 512*512
    u16* wW1  = wWo   + 512 * 512;                   // 2048*512
    u16* wW2  = wW1   + 2048 * 512;                  // 512*2048
    u16* wWh1 = wW2   + 512 * 2048;                  // 2048*512
    u16* wWc1 = wWh1  + 2048 * 512;                  // 2048*512

    dim3 blk(256);

    // ---- weight conversions (fp32 -> bf16) ----
    f2bf_kernel<<<dim3((512*768/4 + 255)/256), blk, 0, stream>>>(Wp, wWp, 512*768/4);
    f2bf_kernel<<<dim3((1536*512/4 + 255)/256), blk, 0, stream>>>(Wqkv, wWqkv, 1536*512/4);
    f2bf_kernel<<<dim3((512*512/4 + 255)/256), blk, 0, stream>>>(Wo, wWo, 512*512/4);
    f2bf_kernel<<<dim3((2048*512/4 + 255)/256), blk, 0, stream>>>(W1, wW1, 2048*512/4);
    f2bf_kernel<<<dim3((512*2048/4 + 255)/256), blk, 0, stream>>>(W2, wW2, 512*2048/4);
    f2bf_kernel<<<dim3((2048*512/4 + 255)/256), blk, 0, stream>>>(Wh1, wWh1, 2048*512/4);
    f2bf_kernel<<<dim3((2048*512/4 + 255)/256), blk, 0, stream>>>(Wc1, wWc1, 2048*512/4);

    // ---- patch embed ----
    patch_kernel<<<dim3(((size_t)MPATCH * PDIM + 255) / 256), blk, 0, stream>>>(x, XP);
    mgemm_kernel<0,1,0,0><<<dim3(DDIM/128, MPATCH/128), blk, 0, stream>>>(
        XP, wWp, bp, nullptr, QKV, MPATCH, DDIM, PDIM);
    assemble_kernel<<<dim3(((size_t)MTOK * DDIM + 255) / 256), blk, 0, stream>>>(
        QKV, clstok, pos, U);

    const int MT = (MTOK + 127) / 128;  // 50 row-tiles

    for (int l = 0; l < NLAYER; l++) {
        ln_kernel<<<dim3((MTOK + 3) / 4), blk, 0, stream>>>(U, ln1g, ln1b, LNB, MTOK);
        mgemm_kernel<0,0,0,0><<<dim3(1536/128, MT), blk, 0, stream>>>(
            LNB, wWqkv, nullptr, nullptr, QKV, MTOK, 1536, DDIM);
        attn_kernel<<<dim3(BBATCH * NHEAD), blk, 0, stream>>>(QKV, LNB);
        mgemm_kernel<0,1,1,0><<<dim3(DDIM/128, MT), blk, 0, stream>>>(
            LNB, wWo, bo, U, U, MTOK, DDIM, DDIM);
        ln_kernel<<<dim3((MTOK + 3) / 4), blk, 0, stream>>>(U, ln2g, ln2b, LNB, MTOK);
        mgemm_kernel<1,1,0,1><<<dim3(MLPDIM/128, MT), blk, 0, stream>>>(
            LNB, wW1, b1, nullptr, HB, MTOK, MLPDIM, DDIM);
        mgemm_kernel<0,1,1,0><<<dim3(DDIM/128, MT), blk, 0, stream>>>(
            HB, wW2, b2, U, U, MTOK, DDIM, MLPDIM);
        ln_kernel<<<dim3((MTOK + 3) / 4), blk, 0, stream>>>(U, lnhg, lnhb, LNB, MTOK);
        mgemm_kernel<1,1,0,1><<<dim3(MLPDIM/128, MT), blk, 0, stream>>>(
            LNB, wWh1, bh1, nullptr, HB, MTOK, MLPDIM, DDIM);
        halt_dot_kernel<<<dim3((MTOK + 3) / 4), blk, 0, stream>>>(HB, Wh2, bh2, HSC);
        halt_mean_cls_kernel<<<dim3(BBATCH), dim3(64), 0, stream>>>(HSC, U, HALTS, CLS, l);
    }

    // ---- head ----
    ln_kernel<<<dim3((BBATCH * NLAYER + 3) / 4), blk, 0, stream>>>(
        CLS, lncg, lncb, CLNB, BBATCH * NLAYER);
    mgemm_kernel<1,1,0,1><<<dim3(MLPDIM/128, 3), blk, 0, stream>>>(
        CLNB, wWc1, bc1, nullptr, HB, BBATCH * NLAYER, MLPDIM, DDIM);
    head_logits_kernel<<<dim3((BBATCH * NLAYER + 3) / 4), blk, 0, stream>>>(
        HB, Wc2, bc2, LOGITS);
    ce_kernel<<<dim3(2), blk, 0, stream>>>(LOGITS, y, CE);
    loss_kernel<<<dim3(1), dim3(64), 0, stream>>>(CE, HALTS, (float*)d_out);
}

// Round 3
// 2419.488 us; speedup vs baseline: 7.2577x; 2.1976x over previous
//
#include <hip/hip_runtime.h>
#include <math.h>

#define BBATCH 32
#define NTOK 197
#define NPATCH 196
#define PDIM 768
#define DDIM 512
#define NHEAD 8
#define DHEAD 64
#define MLPDIM 2048
#define NLAYER 10
#define NCLASS 10
#define MTOK (BBATCH*NTOK)      // 6304
#define MPAD 6400               // padded rows for MFMA A-tiles (50*128)
#define MPATCH (BBATCH*NPATCH)  // 6272
#define QKVROWS (MTOK + 16)     // QKV buffer rows incl. padding for attn tiles

typedef unsigned short u16;
typedef __attribute__((ext_vector_type(8))) short bf16x8;
typedef __attribute__((ext_vector_type(4))) float f32x4;
typedef __attribute__((ext_vector_type(8))) unsigned short ushort8;

__device__ __forceinline__ float gelu_f(float x) {
    return 0.5f * x * (1.0f + erff(x * 0.70710678118654752440f));
}
__device__ __forceinline__ float bf2f(u16 u) {
    union { unsigned int i; float f; } v; v.i = ((unsigned int)u) << 16; return v.f;
}
__device__ __forceinline__ u16 f2bf(float f) {
    union { float f; unsigned int u; } v; v.f = f;
    unsigned int r = v.u + 0x7FFFu + ((v.u >> 16) & 1u);
    return (u16)(r >> 16);
}
__device__ __forceinline__ void gload_lds16(const u16* g, u16* l) {
    __builtin_amdgcn_global_load_lds((const __attribute__((address_space(1))) void*)g,
                                     (__attribute__((address_space(3))) void*)l, 16, 0, 0);
}

// ---------------------------------------------------------------------------
// bf16 MFMA GEMM: C[M,N] = (res?) + act(A[M,K](bf16) @ W[N,K](bf16)^T + bias)
// ---------------------------------------------------------------------------
template<int ACT, int HASB, int HASR, int OUTBF>
__global__ __launch_bounds__(256)
void mgemm_kernel(const u16* __restrict__ A, const u16* __restrict__ W,
                  const float* __restrict__ bias, const float* __restrict__ res,
                  void* __restrict__ Cout, int M, int Nn, int K)
{
    __shared__ u16 As[128 * 64];
    __shared__ u16 Bs[128 * 64];
    const int tid = threadIdx.x;
    const int lane = tid & 63;
    const int wid = tid >> 6;
    const int wr = wid >> 1, wc = wid & 1;
    const int m0 = blockIdx.y * 128, n0 = blockIdx.x * 128;

    f32x4 acc[4][4] = {};

    const int srow = tid >> 3;
    const int dcb  = (tid & 7) << 4;

    for (int k0 = 0; k0 < K; k0 += 64) {
        __syncthreads();
        #pragma unroll
        for (int p = 0; p < 4; ++p) {
            int r = p * 32 + srow;
            int scb = dcb ^ ((r & 7) << 4);
            gload_lds16(A + (size_t)(m0 + r) * K + k0 + (scb >> 1), &As[p * 2048 + tid * 8]);
            gload_lds16(W + (size_t)(n0 + r) * K + k0 + (scb >> 1), &Bs[p * 2048 + tid * 8]);
        }
        __syncthreads();

        #pragma unroll
        for (int kk = 0; kk < 64; kk += 32) {
            const int kb = (kk + ((lane >> 4) << 3)) << 1;
            bf16x8 af[4], bfr[4];
            #pragma unroll
            for (int mi = 0; mi < 4; ++mi) {
                int ar = wr * 64 + mi * 16 + (lane & 15);
                af[mi] = *(const bf16x8*)&As[ar * 64 + ((kb ^ ((ar & 7) << 4)) >> 1)];
            }
            #pragma unroll
            for (int ni = 0; ni < 4; ++ni) {
                int br = wc * 64 + ni * 16 + (lane & 15);
                bfr[ni] = *(const bf16x8*)&Bs[br * 64 + ((kb ^ ((br & 7) << 4)) >> 1)];
            }
            #pragma unroll
            for (int mi = 0; mi < 4; ++mi)
                #pragma unroll
                for (int ni = 0; ni < 4; ++ni)
                    acc[mi][ni] = __builtin_amdgcn_mfma_f32_16x16x32_bf16(
                        af[mi], bfr[ni], acc[mi][ni], 0, 0, 0);
        }
    }

    float* outf = (float*)Cout;
    u16*   outb = (u16*)Cout;
    #pragma unroll
    for (int mi = 0; mi < 4; ++mi) {
        #pragma unroll
        for (int j = 0; j < 4; ++j) {
            int row = m0 + wr * 64 + mi * 16 + ((lane >> 4) << 2) + j;
            if (row >= M) continue;
            #pragma unroll
            for (int ni = 0; ni < 4; ++ni) {
                int col = n0 + wc * 64 + ni * 16 + (lane & 15);
                float v = acc[mi][ni][j];
                if (HASB) v += bias[col];
                if (ACT)  v = gelu_f(v);
                if (HASR) v += res[(size_t)row * Nn + col];
                if (OUTBF) outb[(size_t)row * Nn + col] = f2bf(v);
                else       outf[(size_t)row * Nn + col] = v;
            }
        }
    }
}

__global__ __launch_bounds__(256)
void f2bf_kernel(const float* __restrict__ in, u16* __restrict__ out, int n4)
{
    int i = blockIdx.x * 256 + threadIdx.x;
    if (i >= n4) return;
    float4 v = ((const float4*)in)[i];
    u16 o0 = f2bf(v.x), o1 = f2bf(v.y), o2 = f2bf(v.z), o3 = f2bf(v.w);
    out[i * 4 + 0] = o0; out[i * 4 + 1] = o1; out[i * 4 + 2] = o2; out[i * 4 + 3] = o3;
}

__global__ __launch_bounds__(256)
void ln_kernel(const float* __restrict__ X, const float* __restrict__ g,
               const float* __restrict__ bb, u16* __restrict__ Y, int M)
{
    int wave = (blockIdx.x * 4) + (threadIdx.x >> 6);
    int lane = threadIdx.x & 63;
    if (wave >= M) return;
    const float* x = X + (size_t)wave * DDIM;
    float v[8];
    float s = 0.0f;
    #pragma unroll
    for (int i = 0; i < 8; i++) { v[i] = x[lane + i * 64]; s += v[i]; }
    #pragma unroll
    for (int off = 32; off; off >>= 1) s += __shfl_xor(s, off, 64);
    float mu = s * (1.0f / 512.0f);
    float q = 0.0f;
    #pragma unroll
    for (int i = 0; i < 8; i++) { float d = v[i] - mu; q += d * d; }
    #pragma unroll
    for (int off = 32; off; off >>= 1) q += __shfl_xor(q, off, 64);
    float inv = 1.0f / sqrtf(q * (1.0f / 512.0f) + 1e-5f);
    u16* y = Y + (size_t)wave * DDIM;
    #pragma unroll
    for (int i = 0; i < 8; i++) {
        int c = lane + i * 64;
        y[c] = f2bf((v[i] - mu) * inv * g[c] + bb[c]);
    }
}

__global__ __launch_bounds__(256)
void patch_kernel(const float* __restrict__ x, u16* __restrict__ xp)
{
    size_t idx = (size_t)blockIdx.x * 256 + threadIdx.x;
    if (idx >= (size_t)MPATCH * PDIM) return;
    int pd = (int)(idx % PDIM);
    int bn = (int)(idx / PDIM);
    int n = bn % NPATCH, b = bn / NPATCH;
    int c = pd % 3, pix = pd / 3;
    int px = pix % 16, py = pix / 16;
    int hx = n % 14, hy = n / 14;
    int row = hy * 16 + py, col = hx * 16 + px;
    xp[idx] = f2bf(x[((size_t)(b * 3 + c) * 224 + row) * 224 + col]);
}

__global__ __launch_bounds__(256)
void assemble_kernel(const float* __restrict__ e, const float* __restrict__ clstok,
                     const float* __restrict__ pos, float* __restrict__ U)
{
    size_t idx = (size_t)blockIdx.x * 256 + threadIdx.x;
    if (idx >= (size_t)MTOK * DDIM) return;
    int d = (int)(idx % DDIM);
    int bt = (int)(idx / DDIM);
    int t = bt % NTOK, b = bt / NTOK;
    float v = (t == 0) ? clstok[d] : e[((size_t)b * NPATCH + (t - 1)) * DDIM + d];
    U[idx] = v + pos[t * DDIM + d];
}

// ---------------------------------------------------------------------------
// MFMA attention. Grid 512: 2 blocks per (b,h). See round-2 notes.
// ---------------------------------------------------------------------------
__global__ __launch_bounds__(256)
void attn_mfma_kernel(const u16* __restrict__ qkv, u16* __restrict__ O)
{
    __shared__ u16 Ks[208 * 64];
    __shared__ u16 Vt[64 * 208];
    __shared__ u16 Pl[4 * 16 * 208];

    const int bh = blockIdx.x >> 1;
    const int half = blockIdx.x & 1;
    const int b = bh >> 3, h = bh & 7;
    const int tid = threadIdx.x;
    const int lane = tid & 63, wid = tid >> 6;
    const size_t base = ((size_t)b * NTOK) * 1536 + (size_t)h * 64;

    {
        int j0 = tid >> 3;
        int d0 = (tid & 7) * 8;
        for (int p = 0; p < 7; ++p) {
            int j = p * 32 + j0;
            if (j < 208) {
                bf16x8 v = {};
                if (j < NTOK) v = *(const bf16x8*)&qkv[base + (size_t)j * 1536 + 512 + d0];
                int byt = (j * 128 + d0 * 2) ^ ((j & 7) << 4);
                *(bf16x8*)((char*)Ks + byt) = v;
            }
        }
    }
    {
        int d = tid & 63;
        int jg = tid >> 6;
        for (int j = jg * 52; j < jg * 52 + 52; ++j) {
            u16 v = (j < NTOK) ? qkv[base + (size_t)j * 1536 + 1024 + d] : (u16)0;
            int byt = (d * 416 + j * 2) ^ ((d & 7) << 4);
            *(u16*)((char*)Vt + byt) = v;
        }
    }
    __syncthreads();

    u16* Pw = Pl + wid * 16 * 208;
    const float scale = 0.04419417382415922f;
    const int t0   = half ? 7 : 0;
    const int tcnt = half ? 6 : 7;
    const int g = lane >> 4;
    const int mycol = lane & 15;

    for (int ti = wid; ti < tcnt; ti += 4) {
        const int r0 = (t0 + ti) * 16;
        bf16x8 qf[2];
        #pragma unroll
        for (int ks = 0; ks < 2; ++ks) {
            int row = r0 + mycol;
            int col = ks * 32 + (g << 3);
            qf[ks] = *(const bf16x8*)&qkv[base + (size_t)row * 1536 + col];
        }
        f32x4 s[13];
        #pragma unroll
        for (int ct = 0; ct < 13; ++ct) s[ct] = (f32x4){0.f, 0.f, 0.f, 0.f};
        #pragma unroll
        for (int ks = 0; ks < 2; ++ks) {
            int kbyte = (ks * 32 + (g << 3)) * 2;
            #pragma unroll
            for (int ct = 0; ct < 13; ++ct) {
                int n = ct * 16 + mycol;
                bf16x8 kf = *(const bf16x8*)((char*)Ks + ((n * 128 + kbyte) ^ ((n & 7) << 4)));
                s[ct] = __builtin_amdgcn_mfma_f32_16x16x32_bf16(qf[ks], kf, s[ct], 0, 0, 0);
            }
        }
        float m[4], sum[4];
        #pragma unroll
        for (int j = 0; j < 4; ++j) m[j] = -1e30f;
        #pragma unroll
        for (int ct = 0; ct < 13; ++ct) {
            bool valid = (ct * 16 + mycol) < NTOK;
            #pragma unroll
            for (int j = 0; j < 4; ++j) {
                float v = valid ? s[ct][j] * scale : -1e30f;
                s[ct][j] = v;
                m[j] = fmaxf(m[j], v);
            }
        }
        #pragma unroll
        for (int off = 1; off < 16; off <<= 1)
            #pragma unroll
            for (int j = 0; j < 4; ++j) m[j] = fmaxf(m[j], __shfl_xor(m[j], off, 64));
        #pragma unroll
        for (int j = 0; j < 4; ++j) sum[j] = 0.0f;
        #pragma unroll
        for (int ct = 0; ct < 13; ++ct)
            #pragma unroll
            for (int j = 0; j < 4; ++j) {
                float e = expf(s[ct][j] - m[j]);
                s[ct][j] = e;
                sum[j] += e;
            }
        #pragma unroll
        for (int off = 1; off < 16; off <<= 1)
            #pragma unroll
            for (int j = 0; j < 4; ++j) sum[j] += __shfl_xor(sum[j], off, 64);
        float inv[4];
        #pragma unroll
        for (int j = 0; j < 4; ++j) inv[j] = 1.0f / sum[j];
        #pragma unroll
        for (int ct = 0; ct < 13; ++ct) {
            int col = ct * 16 + mycol;
            #pragma unroll
            for (int j = 0; j < 4; ++j) {
                int row = (g << 2) + j;
                int byt = (row * 416 + col * 2) ^ ((row & 7) << 4);
                *(u16*)((char*)Pw + byt) = f2bf(s[ct][j] * inv[j]);
            }
        }
        #pragma unroll
        for (int nt = 0; nt < 4; ++nt) {
            f32x4 o = (f32x4){0.f, 0.f, 0.f, 0.f};
            #pragma unroll
            for (int ks = 0; ks < 7; ++ks) {
                bf16x8 pf = {}, vf = {};
                bool live = !(ks == 6 && g >= 2);
                if (live) {
                    int kbyte = (ks * 32 + (g << 3)) * 2;
                    pf = *(const bf16x8*)((char*)Pw + ((mycol * 416 + kbyte) ^ ((mycol & 7) << 4)));
                    int vrow = nt * 16 + mycol;
                    vf = *(const bf16x8*)((char*)Vt + ((vrow * 416 + kbyte) ^ ((vrow & 7) << 4)));
                }
                o = __builtin_amdgcn_mfma_f32_16x16x32_bf16(pf, vf, o, 0, 0, 0);
            }
            #pragma unroll
            for (int j = 0; j < 4; ++j) {
                int grow = r0 + (g << 2) + j;
                if (grow < NTOK)
                    O[((size_t)b * NTOK + grow) * DDIM + h * 64 + nt * 16 + mycol] = f2bf(o[j]);
            }
        }
    }
}

__global__ __launch_bounds__(256)
void halt_dot_kernel(const u16* __restrict__ Hh, const float* __restrict__ Wh2,
                     const float* __restrict__ bh2, float* __restrict__ hsc)
{
    int wave = (blockIdx.x * 4) + (threadIdx.x >> 6);
    int lane = threadIdx.x & 63;
    if (wave >= MTOK) return;
    const u16* row = Hh + (size_t)wave * MLPDIM;
    float s = 0.0f;
    #pragma unroll
    for (int i = 0; i < 4; i++) {
        ushort8 v = *(const ushort8*)&row[i * 512 + lane * 8];
        #pragma unroll
        for (int j = 0; j < 8; j++)
            s = fmaf(bf2f(v[j]), Wh2[i * 512 + lane * 8 + j], s);
    }
    #pragma unroll
    for (int off = 32; off; off >>= 1) s += __shfl_xor(s, off, 64);
    if (lane == 0) hsc[wave] = 1.0f / (1.0f + expf(-(s + bh2[0])));
}

__global__ __launch_bounds__(64)
void halt_mean_cls_kernel(const float* __restrict__ hsc, const float* __restrict__ U,
                          float* __restrict__ halts, float* __restrict__ cls, int l)
{
    int b = blockIdx.x, lane = threadIdx.x;
    float s = 0.0f;
    for (int t = lane; t < NTOK; t += 64) s += hsc[b * NTOK + t];
    #pragma unroll
    for (int off = 32; off; off >>= 1) s += __shfl_xor(s, off, 64);
    if (lane == 0) halts[b * NLAYER + l] = s * (1.0f / (float)NTOK);
    for (int d = lane; d < DDIM; d += 64)
        cls[((size_t)b * NLAYER + l) * DDIM + d] = U[(size_t)b * NTOK * DDIM + d];
}

__global__ __launch_bounds__(256)
void head_logits_kernel(const u16* __restrict__ Hh, const float* __restrict__ Wc2,
                        const float* __restrict__ bc2, float* __restrict__ logits)
{
    int wave = (blockIdx.x * 4) + (threadIdx.x >> 6);
    int lane = threadIdx.x & 63;
    if (wave >= BBATCH * NLAYER) return;
    const u16* row = Hh + (size_t)wave * MLPDIM;
    float rv[32];
    #pragma unroll
    for (int i = 0; i < 32; i++) rv[i] = bf2f(row[lane + i * 64]);
    #pragma unroll
    for (int c = 0; c < NCLASS; c++) {
        float s = 0.0f;
        #pragma unroll
        for (int i = 0; i < 32; i++) s = fmaf(rv[i], Wc2[c * MLPDIM + lane + i * 64], s);
        #pragma unroll
        for (int off = 32; off; off >>= 1) s += __shfl_xor(s, off, 64);
        if (lane == 0) logits[wave * NCLASS + c] = s + bc2[c];
    }
}

__global__ __launch_bounds__(256)
void ce_kernel(const float* __restrict__ logits, const int* __restrict__ y,
               float* __restrict__ ce)
{
    int r = blockIdx.x * 256 + threadIdx.x;
    if (r >= BBATCH * NLAYER) return;
    const float* lg = logits + (size_t)r * NCLASS;
    float mx = lg[0];
    #pragma unroll
    for (int i = 1; i < NCLASS; i++) mx = fmaxf(mx, lg[i]);
    float s = 0.0f;
    #pragma unroll
    for (int i = 0; i < NCLASS; i++) s += expf(lg[i] - mx);
    int lab = y[r / NLAYER];
    ce[r] = -(lg[lab] - mx - logf(s));
}

__global__ __launch_bounds__(64)
void loss_kernel(const float* __restrict__ ce, const float* __restrict__ halts,
                 float* __restrict__ out)
{
    int b = threadIdx.x;
    float total = 0.0f;
    if (b < BBATCH) {
        const float* c = ce + b * NLAYER;
        int idx = 0; float mn = c[0];
        for (int l = 1; l < NLAYER; l++) if (c[l] < mn) { mn = c[l]; idx = l; }
        idx += 1;
        float acc = 0.0f;
        for (int l = 0; l < idx; l++) {
            acc += c[l];
            float p = halts[b * NLAYER + l];
            p = fminf(fmaxf(p, 1e-7f), 1.0f - 1e-7f);
            float hl = (l == idx - 1) ? 0.0f : 1.0f;
            acc += -(hl * logf(p) + (1.0f - hl) * log1pf(-p));
        }
        total = acc / (float)idx;
    }
    #pragma unroll
    for (int off = 32; off; off >>= 1) total += __shfl_xor(total, off, 64);
    if (threadIdx.x == 0) out[0] = total * (1.0f / (float)BBATCH);
}

extern "C" void kernel_launch(void* const* d_in, const int* in_sizes, int n_in,
                              void* d_out, int out_size, void* d_ws, size_t ws_size,
                              hipStream_t stream)
{
    const float* x      = (const float*)d_in[0];
    const int*   y      = (const int*)d_in[1];
    const float* pos    = (const float*)d_in[2];
    const float* clstok = (const float*)d_in[3];
    const float* Wp     = (const float*)d_in[4];
    const float* bp     = (const float*)d_in[5];
    const float* Wqkv   = (const float*)d_in[6];
    const float* Wo     = (const float*)d_in[7];
    const float* bo     = (const float*)d_in[8];
    const float* ln1g   = (const float*)d_in[9];
    const float* ln1b   = (const float*)d_in[10];
    const float* ln2g   = (const float*)d_in[11];
    const float* ln2b   = (const float*)d_in[12];
    const float* W1     = (const float*)d_in[13];
    const float* b1     = (const float*)d_in[14];
    const float* W2     = (const float*)d_in[15];
    const float* b2     = (const float*)d_in[16];
    const float* lnhg   = (const float*)d_in[17];
    const float* lnhb   = (const float*)d_in[18];
    const float* Wh1    = (const float*)d_in[19];
    const float* bh1    = (const float*)d_in[20];
    const float* Wh2    = (const float*)d_in[21];
    const float* bh2    = (const float*)d_in[22];
    const float* lncg   = (const float*)d_in[23];
    const float* lncb   = (const float*)d_in[24];
    const float* Wc1    = (const float*)d_in[25];
    const float* bc1    = (const float*)d_in[26];
    const float* Wc2    = (const float*)d_in[27];
    const float* bc2    = (const float*)d_in[28];

    // ---- workspace layout ----
    float* U      = (float*)d_ws;                    // MTOK*512
    float* EMB    = U + (size_t)MTOK * DDIM;         // MPATCH*512 fp32 patch-embed out
    float* CLS    = EMB + (size_t)MPATCH * DDIM;     // 320*512
    float* LOGITS = CLS + (size_t)BBATCH * NLAYER * DDIM;
    float* CE     = LOGITS + BBATCH * NLAYER * NCLASS;
    float* HSC    = CE + BBATCH * NLAYER;
    float* HALTS  = HSC + MTOK;
    u16* QKVb = (u16*)(HALTS + BBATCH * NLAYER + 32);// QKVROWS*1536 bf16
    u16* LNB  = QKVb + (size_t)QKVROWS * 1536;       // MPAD*512 (ln out / attn out)
    u16* HB   = LNB + (size_t)MPAD * DDIM;           // MPAD*2048
    u16* XP   = HB + (size_t)MPAD * MLPDIM;          // 6272*768
    u16* CLNB = XP + (size_t)MPATCH * PDIM;          // 384*512
    u16* wWp  = CLNB + 384 * DDIM;
    u16* wWqkv= wWp   + 512 * 768;
    u16* wWo  = wWqkv + 1536 * 512;
    u16* wW1  = wWo   + 512 * 512;
    u16* wW2  = wW1   + 2048 * 512;
    u16* wWh1 = wW2   + 512 * 2048;
    u16* wWc1 = wWh1  + 2048 * 512;

    dim3 blk(256);

    f2bf_kernel<<<dim3((512*768/4 + 255)/256), blk, 0, stream>>>(Wp, wWp, 512*768/4);
    f2bf_kernel<<<dim3((1536*512/4 + 255)/256), blk, 0, stream>>>(Wqkv, wWqkv, 1536*512/4);
    f2bf_kernel<<<dim3((512*512/4 + 255)/256), blk, 0, stream>>>(Wo, wWo, 512*512/4);
    f2bf_kernel<<<dim3((2048*512/4 + 255)/256), blk, 0, stream>>>(W1, wW1, 2048*512/4);
    f2bf_kernel<<<dim3((512*2048/4 + 255)/256), blk, 0, stream>>>(W2, wW2, 512*2048/4);
    f2bf_kernel<<<dim3((2048*512/4 + 255)/256), blk, 0, stream>>>(Wh1, wWh1, 2048*512/4);
    f2bf_kernel<<<dim3((2048*512/4 + 255)/256), blk, 0, stream>>>(Wc1, wWc1, 2048*512/4);

    patch_kernel<<<dim3(((size_t)MPATCH * PDIM + 255) / 256), blk, 0, stream>>>(x, XP);
    mgemm_kernel<0,1,0,0><<<dim3(DDIM/128, MPATCH/128), blk, 0, stream>>>(
        XP, wWp, bp, nullptr, (void*)EMB, MPATCH, DDIM, PDIM);
    assemble_kernel<<<dim3(((size_t)MTOK * DDIM + 255) / 256), blk, 0, stream>>>(
        EMB, clstok, pos, U);

    const int MT = (MTOK + 127) / 128;  // 50

    for (int l = 0; l < NLAYER; l++) {
        ln_kernel<<<dim3((MTOK + 3) / 4), blk, 0, stream>>>(U, ln1g, ln1b, LNB, MTOK);
        mgemm_kernel<0,0,0,1><<<dim3(1536/128, MT), blk, 0, stream>>>(
            LNB, wWqkv, nullptr, nullptr, (void*)QKVb, MTOK, 1536, DDIM);
        attn_mfma_kernel<<<dim3(512), blk, 0, stream>>>(QKVb, LNB);
        mgemm_kernel<0,1,1,0><<<dim3(DDIM/128, MT), blk, 0, stream>>>(
            LNB, wWo, bo, U, (void*)U, MTOK, DDIM, DDIM);
        ln_kernel<<<dim3((MTOK + 3) / 4), blk, 0, stream>>>(U, ln2g, ln2b, LNB, MTOK);
        mgemm_kernel<1,1,0,1><<<dim3(MLPDIM/128, MT), blk, 0, stream>>>(
            LNB, wW1, b1, nullptr, (void*)HB, MTOK, MLPDIM, DDIM);
        mgemm_kernel<0,1,1,0><<<dim3(DDIM/128, MT), blk, 0, stream>>>(
            HB, wW2, b2, U, (void*)U, MTOK, DDIM, MLPDIM);
        ln_kernel<<<dim3((MTOK + 3) / 4), blk, 0, stream>>>(U, lnhg, lnhb, LNB, MTOK);
        mgemm_kernel<1,1,0,1><<<dim3(MLPDIM/128, MT), blk, 0, stream>>>(
            LNB, wWh1, bh1, nullptr, (void*)HB, MTOK, MLPDIM, DDIM);
        halt_dot_kernel<<<dim3((MTOK + 3) / 4), blk, 0, stream>>>(HB, Wh2, bh2, HSC);
        halt_mean_cls_kernel<<<dim3(BBATCH), dim3(64), 0, stream>>>(HSC, U, HALTS, CLS, l);
    }

    ln_kernel<<<dim3((BBATCH * NLAYER + 3) / 4), blk, 0, stream>>>(
        CLS, lncg, lncb, CLNB, BBATCH * NLAYER);
    mgemm_kernel<1,1,0,1><<<dim3(MLPDIM/128, 3), blk, 0, stream>>>(
        CLNB, wWc1, bc1, nullptr, (void*)HB, BBATCH * NLAYER, MLPDIM, DDIM);
    head_logits_kernel<<<dim3((BBATCH * NLAYER + 3) / 4), blk, 0, stream>>>(
        HB, Wc2, bc2, LOGITS);
    ce_kernel<<<dim3(2), blk, 0, stream>>>(LOGITS, y, CE);
    loss_kernel<<<dim3(1), dim3(64), 0, stream>>>(CE, HALTS, (float*)d_out);
}

// Round 4
// 2341.820 us; speedup vs baseline: 7.4984x; 1.0332x over previous
//
#include <hip/hip_runtime.h>
#include <math.h>

#define BBATCH 32
#define NTOK 197
#define NPATCH 196
#define PDIM 768
#define DDIM 512
#define NHEAD 8
#define DHEAD 64
#define MLPDIM 2048
#define NLAYER 10
#define NCLASS 10
#define MTOK (BBATCH*NTOK)      // 6304
#define MPAD 6400               // padded rows for MFMA A-tiles (50*128)
#define MPATCH (BBATCH*NPATCH)  // 6272
#define QKVROWS (MTOK + 16)     // QKV buffer rows incl. padding for attn tiles

typedef unsigned short u16;
typedef __attribute__((ext_vector_type(8))) short bf16x8;
typedef __attribute__((ext_vector_type(4))) float f32x4;
typedef __attribute__((ext_vector_type(8))) unsigned short ushort8;

__device__ __forceinline__ float gelu_f(float x) {
    return 0.5f * x * (1.0f + erff(x * 0.70710678118654752440f));
}
__device__ __forceinline__ float bf2f(u16 u) {
    union { unsigned int i; float f; } v; v.i = ((unsigned int)u) << 16; return v.f;
}
__device__ __forceinline__ u16 f2bf(float f) {
    union { float f; unsigned int u; } v; v.f = f;
    unsigned int r = v.u + 0x7FFFu + ((v.u >> 16) & 1u);
    return (u16)(r >> 16);
}
__device__ __forceinline__ void gload_lds16(const u16* g, u16* l) {
    __builtin_amdgcn_global_load_lds((const __attribute__((address_space(1))) void*)g,
                                     (__attribute__((address_space(3))) void*)l, 16, 0, 0);
}

// ---------------------------------------------------------------------------
// bf16 MFMA GEMM, double-buffered single-barrier pipeline (T3 minimal):
//   prologue: STAGE(buf0); vmcnt(0); barrier
//   loop:     STAGE(next); COMPUTE(cur); vmcnt(0); barrier; swap
// C[M,N] = (res?) + act(A @ W^T + bias).  HALT variant: skip C write, reduce
// gelu(acc+bias).Wh2 per row and atomicAdd into Cout (float per token).
// ---------------------------------------------------------------------------
template<int ACT, int HASB, int HASR, int OUTBF, int HALT>
__global__ __launch_bounds__(256)
void mgemm_kernel(const u16* __restrict__ A, const u16* __restrict__ W,
                  const float* __restrict__ bias, const float* __restrict__ res,
                  void* __restrict__ Cout, int M, int Nn, int K)
{
    __shared__ u16 As[2][128 * 64];
    __shared__ u16 Bs[2][128 * 64];
    const int tid = threadIdx.x;
    const int lane = tid & 63;
    const int wid = tid >> 6;
    const int wr = wid >> 1, wc = wid & 1;
    const int m0 = blockIdx.y * 128, n0 = blockIdx.x * 128;

    f32x4 acc[4][4] = {};

    const int srow = tid >> 3;
    const int dcb  = (tid & 7) << 4;

    auto stage = [&](int buf, int k0) {
        #pragma unroll
        for (int p = 0; p < 4; ++p) {
            int r = p * 32 + srow;
            int scb = dcb ^ ((r & 7) << 4);
            gload_lds16(A + (size_t)(m0 + r) * K + k0 + (scb >> 1), &As[buf][p * 2048 + tid * 8]);
            gload_lds16(W + (size_t)(n0 + r) * K + k0 + (scb >> 1), &Bs[buf][p * 2048 + tid * 8]);
        }
    };
    auto compute = [&](int buf) {
        #pragma unroll
        for (int kk = 0; kk < 64; kk += 32) {
            const int kb = (kk + ((lane >> 4) << 3)) << 1;
            bf16x8 af[4], bfr[4];
            #pragma unroll
            for (int mi = 0; mi < 4; ++mi) {
                int ar = wr * 64 + mi * 16 + (lane & 15);
                af[mi] = *(const bf16x8*)&As[buf][ar * 64 + ((kb ^ ((ar & 7) << 4)) >> 1)];
            }
            #pragma unroll
            for (int ni = 0; ni < 4; ++ni) {
                int br = wc * 64 + ni * 16 + (lane & 15);
                bfr[ni] = *(const bf16x8*)&Bs[buf][br * 64 + ((kb ^ ((br & 7) << 4)) >> 1)];
            }
            #pragma unroll
            for (int mi = 0; mi < 4; ++mi)
                #pragma unroll
                for (int ni = 0; ni < 4; ++ni)
                    acc[mi][ni] = __builtin_amdgcn_mfma_f32_16x16x32_bf16(
                        af[mi], bfr[ni], acc[mi][ni], 0, 0, 0);
        }
    };

    const int NT = K >> 6;
    stage(0, 0);
    asm volatile("s_waitcnt vmcnt(0)" ::: "memory");
    __builtin_amdgcn_s_barrier();
    int cur = 0;
    #pragma unroll 1
    for (int t = 0; t < NT - 1; ++t) {
        stage(cur ^ 1, (t + 1) << 6);
        compute(cur);
        asm volatile("s_waitcnt vmcnt(0)" ::: "memory");
        __builtin_amdgcn_s_barrier();
        cur ^= 1;
    }
    compute(cur);

    if (HALT) {
        // halt head: per-row partial = sum_cols gelu(acc+bias)*Wh2[col]
        const float* Wh2v = res;
        float* hout = (float*)Cout;
        #pragma unroll
        for (int mi = 0; mi < 4; ++mi) {
            #pragma unroll
            for (int j = 0; j < 4; ++j) {
                int row = m0 + wr * 64 + mi * 16 + ((lane >> 4) << 2) + j;
                float part = 0.0f;
                #pragma unroll
                for (int ni = 0; ni < 4; ++ni) {
                    int col = n0 + wc * 64 + ni * 16 + (lane & 15);
                    float v = gelu_f(acc[mi][ni][j] + bias[col]);
                    part += v * Wh2v[col];
                }
                #pragma unroll
                for (int off = 1; off < 16; off <<= 1) part += __shfl_xor(part, off, 64);
                if ((lane & 15) == 0 && row < M) atomicAdd(&hout[row], part);
            }
        }
        return;
    }

    float* outf = (float*)Cout;
    u16*   outb = (u16*)Cout;
    #pragma unroll
    for (int mi = 0; mi < 4; ++mi) {
        #pragma unroll
        for (int j = 0; j < 4; ++j) {
            int row = m0 + wr * 64 + mi * 16 + ((lane >> 4) << 2) + j;
            if (row >= M) continue;
            #pragma unroll
            for (int ni = 0; ni < 4; ++ni) {
                int col = n0 + wc * 64 + ni * 16 + (lane & 15);
                float v = acc[mi][ni][j];
                if (HASB) v += bias[col];
                if (ACT)  v = gelu_f(v);
                if (HASR) v += res[(size_t)row * Nn + col];
                if (OUTBF) outb[(size_t)row * Nn + col] = f2bf(v);
                else       outf[(size_t)row * Nn + col] = v;
            }
        }
    }
}

__global__ __launch_bounds__(256)
void f2bf_kernel(const float* __restrict__ in, u16* __restrict__ out, int n4)
{
    int i = blockIdx.x * 256 + threadIdx.x;
    if (i >= n4) return;
    float4 v = ((const float4*)in)[i];
    u16 o0 = f2bf(v.x), o1 = f2bf(v.y), o2 = f2bf(v.z), o3 = f2bf(v.w);
    out[i * 4 + 0] = o0; out[i * 4 + 1] = o1; out[i * 4 + 2] = o2; out[i * 4 + 3] = o3;
}

__global__ __launch_bounds__(256)
void ln_kernel(const float* __restrict__ X, const float* __restrict__ g,
               const float* __restrict__ bb, u16* __restrict__ Y, int M)
{
    int wave = (blockIdx.x * 4) + (threadIdx.x >> 6);
    int lane = threadIdx.x & 63;
    if (wave >= M) return;
    const float* x = X + (size_t)wave * DDIM;
    float v[8];
    float s = 0.0f;
    #pragma unroll
    for (int i = 0; i < 8; i++) { v[i] = x[lane + i * 64]; s += v[i]; }
    #pragma unroll
    for (int off = 32; off; off >>= 1) s += __shfl_xor(s, off, 64);
    float mu = s * (1.0f / 512.0f);
    float q = 0.0f;
    #pragma unroll
    for (int i = 0; i < 8; i++) { float d = v[i] - mu; q += d * d; }
    #pragma unroll
    for (int off = 32; off; off >>= 1) q += __shfl_xor(q, off, 64);
    float inv = 1.0f / sqrtf(q * (1.0f / 512.0f) + 1e-5f);
    u16* y = Y + (size_t)wave * DDIM;
    #pragma unroll
    for (int i = 0; i < 8; i++) {
        int c = lane + i * 64;
        y[c] = f2bf((v[i] - mu) * inv * g[c] + bb[c]);
    }
}

__global__ __launch_bounds__(256)
void patch_kernel(const float* __restrict__ x, u16* __restrict__ xp)
{
    size_t idx = (size_t)blockIdx.x * 256 + threadIdx.x;
    if (idx >= (size_t)MPATCH * PDIM) return;
    int pd = (int)(idx % PDIM);
    int bn = (int)(idx / PDIM);
    int n = bn % NPATCH, b = bn / NPATCH;
    int c = pd % 3, pix = pd / 3;
    int px = pix % 16, py = pix / 16;
    int hx = n % 14, hy = n / 14;
    int row = hy * 16 + py, col = hx * 16 + px;
    xp[idx] = f2bf(x[((size_t)(b * 3 + c) * 224 + row) * 224 + col]);
}

__global__ __launch_bounds__(256)
void assemble_kernel(const float* __restrict__ e, const float* __restrict__ clstok,
                     const float* __restrict__ pos, float* __restrict__ U)
{
    size_t idx = (size_t)blockIdx.x * 256 + threadIdx.x;
    if (idx >= (size_t)MTOK * DDIM) return;
    int d = (int)(idx % DDIM);
    int bt = (int)(idx / DDIM);
    int t = bt % NTOK, b = bt / NTOK;
    float v = (t == 0) ? clstok[d] : e[((size_t)b * NPATCH + (t - 1)) * DDIM + d];
    U[idx] = v + pos[t * DDIM + d];
}

// ---------------------------------------------------------------------------
// MFMA attention. Grid 512: 2 blocks per (b,h).
// ---------------------------------------------------------------------------
__global__ __launch_bounds__(256)
void attn_mfma_kernel(const u16* __restrict__ qkv, u16* __restrict__ O)
{
    __shared__ u16 Ks[208 * 64];
    __shared__ u16 Vt[64 * 208];
    __shared__ u16 Pl[4 * 16 * 208];

    const int bh = blockIdx.x >> 1;
    const int half = blockIdx.x & 1;
    const int b = bh >> 3, h = bh & 7;
    const int tid = threadIdx.x;
    const int lane = tid & 63, wid = tid >> 6;
    const size_t base = ((size_t)b * NTOK) * 1536 + (size_t)h * 64;

    {
        int j0 = tid >> 3;
        int d0 = (tid & 7) * 8;
        for (int p = 0; p < 7; ++p) {
            int j = p * 32 + j0;
            if (j < 208) {
                bf16x8 v = {};
                if (j < NTOK) v = *(const bf16x8*)&qkv[base + (size_t)j * 1536 + 512 + d0];
                int byt = (j * 128 + d0 * 2) ^ ((j & 7) << 4);
                *(bf16x8*)((char*)Ks + byt) = v;
            }
        }
    }
    {
        int d = tid & 63;
        int jg = tid >> 6;
        for (int j = jg * 52; j < jg * 52 + 52; ++j) {
            u16 v = (j < NTOK) ? qkv[base + (size_t)j * 1536 + 1024 + d] : (u16)0;
            int byt = (d * 416 + j * 2) ^ ((d & 7) << 4);
            *(u16*)((char*)Vt + byt) = v;
        }
    }
    __syncthreads();

    u16* Pw = Pl + wid * 16 * 208;
    const float scale = 0.04419417382415922f;
    const int t0   = half ? 7 : 0;
    const int tcnt = half ? 6 : 7;
    const int g = lane >> 4;
    const int mycol = lane & 15;

    for (int ti = wid; ti < tcnt; ti += 4) {
        const int r0 = (t0 + ti) * 16;
        bf16x8 qf[2];
        #pragma unroll
        for (int ks = 0; ks < 2; ++ks) {
            int row = r0 + mycol;
            int col = ks * 32 + (g << 3);
            qf[ks] = *(const bf16x8*)&qkv[base + (size_t)row * 1536 + col];
        }
        f32x4 s[13];
        #pragma unroll
        for (int ct = 0; ct < 13; ++ct) s[ct] = (f32x4){0.f, 0.f, 0.f, 0.f};
        #pragma unroll
        for (int ks = 0; ks < 2; ++ks) {
            int kbyte = (ks * 32 + (g << 3)) * 2;
            #pragma unroll
            for (int ct = 0; ct < 13; ++ct) {
                int n = ct * 16 + mycol;
                bf16x8 kf = *(const bf16x8*)((char*)Ks + ((n * 128 + kbyte) ^ ((n & 7) << 4)));
                s[ct] = __builtin_amdgcn_mfma_f32_16x16x32_bf16(qf[ks], kf, s[ct], 0, 0, 0);
            }
        }
        float m[4], sum[4];
        #pragma unroll
        for (int j = 0; j < 4; ++j) m[j] = -1e30f;
        #pragma unroll
        for (int ct = 0; ct < 13; ++ct) {
            bool valid = (ct * 16 + mycol) < NTOK;
            #pragma unroll
            for (int j = 0; j < 4; ++j) {
                float v = valid ? s[ct][j] * scale : -1e30f;
                s[ct][j] = v;
                m[j] = fmaxf(m[j], v);
            }
        }
        #pragma unroll
        for (int off = 1; off < 16; off <<= 1)
            #pragma unroll
            for (int j = 0; j < 4; ++j) m[j] = fmaxf(m[j], __shfl_xor(m[j], off, 64));
        #pragma unroll
        for (int j = 0; j < 4; ++j) sum[j] = 0.0f;
        #pragma unroll
        for (int ct = 0; ct < 13; ++ct)
            #pragma unroll
            for (int j = 0; j < 4; ++j) {
                float e = expf(s[ct][j] - m[j]);
                s[ct][j] = e;
                sum[j] += e;
            }
        #pragma unroll
        for (int off = 1; off < 16; off <<= 1)
            #pragma unroll
            for (int j = 0; j < 4; ++j) sum[j] += __shfl_xor(sum[j], off, 64);
        float inv[4];
        #pragma unroll
        for (int j = 0; j < 4; ++j) inv[j] = 1.0f / sum[j];
        #pragma unroll
        for (int ct = 0; ct < 13; ++ct) {
            int col = ct * 16 + mycol;
            #pragma unroll
            for (int j = 0; j < 4; ++j) {
                int row = (g << 2) + j;
                int byt = (row * 416 + col * 2) ^ ((row & 7) << 4);
                *(u16*)((char*)Pw + byt) = f2bf(s[ct][j] * inv[j]);
            }
        }
        #pragma unroll
        for (int nt = 0; nt < 4; ++nt) {
            f32x4 o = (f32x4){0.f, 0.f, 0.f, 0.f};
            #pragma unroll
            for (int ks = 0; ks < 7; ++ks) {
                bf16x8 pf = {}, vf = {};
                bool live = !(ks == 6 && g >= 2);
                if (live) {
                    int kbyte = (ks * 32 + (g << 3)) * 2;
                    pf = *(const bf16x8*)((char*)Pw + ((mycol * 416 + kbyte) ^ ((mycol & 7) << 4)));
                    int vrow = nt * 16 + mycol;
                    vf = *(const bf16x8*)((char*)Vt + ((vrow * 416 + kbyte) ^ ((vrow & 7) << 4)));
                }
                o = __builtin_amdgcn_mfma_f32_16x16x32_bf16(pf, vf, o, 0, 0, 0);
            }
            #pragma unroll
            for (int j = 0; j < 4; ++j) {
                int grow = r0 + (g << 2) + j;
                if (grow < NTOK)
                    O[((size_t)b * NTOK + grow) * DDIM + h * 64 + nt * 16 + mycol] = f2bf(o[j]);
            }
        }
    }
}

// halts[b][l] = mean_t sigmoid(hsc_raw + bh2);  cls[b][l][:] = U[b*197+0][:]
__global__ __launch_bounds__(64)
void halt_mean_cls_kernel(const float* __restrict__ hsc, const float* __restrict__ bh2,
                          const float* __restrict__ U,
                          float* __restrict__ halts, float* __restrict__ cls, int l)
{
    int b = blockIdx.x, lane = threadIdx.x;
    float bb = bh2[0];
    float s = 0.0f;
    for (int t = lane; t < NTOK; t += 64) {
        float raw = hsc[b * NTOK + t] + bb;
        s += 1.0f / (1.0f + expf(-raw));
    }
    #pragma unroll
    for (int off = 32; off; off >>= 1) s += __shfl_xor(s, off, 64);
    if (lane == 0) halts[b * NLAYER + l] = s * (1.0f / (float)NTOK);
    for (int d = lane; d < DDIM; d += 64)
        cls[((size_t)b * NLAYER + l) * DDIM + d] = U[(size_t)b * NTOK * DDIM + d];
}

__global__ __launch_bounds__(256)
void head_logits_kernel(const u16* __restrict__ Hh, const float* __restrict__ Wc2,
                        const float* __restrict__ bc2, float* __restrict__ logits)
{
    int wave = (blockIdx.x * 4) + (threadIdx.x >> 6);
    int lane = threadIdx.x & 63;
    if (wave >= BBATCH * NLAYER) return;
    const u16* row = Hh + (size_t)wave * MLPDIM;
    float rv[32];
    #pragma unroll
    for (int i = 0; i < 32; i++) rv[i] = bf2f(row[lane + i * 64]);
    #pragma unroll
    for (int c = 0; c < NCLASS; c++) {
        float s = 0.0f;
        #pragma unroll
        for (int i = 0; i < 32; i++) s = fmaf(rv[i], Wc2[c * MLPDIM + lane + i * 64], s);
        #pragma unroll
        for (int off = 32; off; off >>= 1) s += __shfl_xor(s, off, 64);
        if (lane == 0) logits[wave * NCLASS + c] = s + bc2[c];
    }
}

__global__ __launch_bounds__(256)
void ce_kernel(const float* __restrict__ logits, const int* __restrict__ y,
               float* __restrict__ ce)
{
    int r = blockIdx.x * 256 + threadIdx.x;
    if (r >= BBATCH * NLAYER) return;
    const float* lg = logits + (size_t)r * NCLASS;
    float mx = lg[0];
    #pragma unroll
    for (int i = 1; i < NCLASS; i++) mx = fmaxf(mx, lg[i]);
    float s = 0.0f;
    #pragma unroll
    for (int i = 0; i < NCLASS; i++) s += expf(lg[i] - mx);
    int lab = y[r / NLAYER];
    ce[r] = -(lg[lab] - mx - logf(s));
}

__global__ __launch_bounds__(64)
void loss_kernel(const float* __restrict__ ce, const float* __restrict__ halts,
                 float* __restrict__ out)
{
    int b = threadIdx.x;
    float total = 0.0f;
    if (b < BBATCH) {
        const float* c = ce + b * NLAYER;
        int idx = 0; float mn = c[0];
        for (int l = 1; l < NLAYER; l++) if (c[l] < mn) { mn = c[l]; idx = l; }
        idx += 1;
        float acc = 0.0f;
        for (int l = 0; l < idx; l++) {
            acc += c[l];
            float p = halts[b * NLAYER + l];
            p = fminf(fmaxf(p, 1e-7f), 1.0f - 1e-7f);
            float hl = (l == idx - 1) ? 0.0f : 1.0f;
            acc += -(hl * logf(p) + (1.0f - hl) * log1pf(-p));
        }
        total = acc / (float)idx;
    }
    #pragma unroll
    for (int off = 32; off; off >>= 1) total += __shfl_xor(total, off, 64);
    if (threadIdx.x == 0) out[0] = total * (1.0f / (float)BBATCH);
}

extern "C" void kernel_launch(void* const* d_in, const int* in_sizes, int n_in,
                              void* d_out, int out_size, void* d_ws, size_t ws_size,
                              hipStream_t stream)
{
    const float* x      = (const float*)d_in[0];
    const int*   y      = (const int*)d_in[1];
    const float* pos    = (const float*)d_in[2];
    const float* clstok = (const float*)d_in[3];
    const float* Wp     = (const float*)d_in[4];
    const float* bp     = (const float*)d_in[5];
    const float* Wqkv   = (const float*)d_in[6];
    const float* Wo     = (const float*)d_in[7];
    const float* bo     = (const float*)d_in[8];
    const float* ln1g   = (const float*)d_in[9];
    const float* ln1b   = (const float*)d_in[10];
    const float* ln2g   = (const float*)d_in[11];
    const float* ln2b   = (const float*)d_in[12];
    const float* W1     = (const float*)d_in[13];
    const float* b1     = (const float*)d_in[14];
    const float* W2     = (const float*)d_in[15];
    const float* b2     = (const float*)d_in[16];
    const float* lnhg   = (const float*)d_in[17];
    const float* lnhb   = (const float*)d_in[18];
    const float* Wh1    = (const float*)d_in[19];
    const float* bh1    = (const float*)d_in[20];
    const float* Wh2    = (const float*)d_in[21];
    const float* bh2    = (const float*)d_in[22];
    const float* lncg   = (const float*)d_in[23];
    const float* lncb   = (const float*)d_in[24];
    const float* Wc1    = (const float*)d_in[25];
    const float* bc1    = (const float*)d_in[26];
    const float* Wc2    = (const float*)d_in[27];
    const float* bc2    = (const float*)d_in[28];

    // ---- workspace layout ----
    float* U      = (float*)d_ws;                    // MTOK*512
    float* EMB    = U + (size_t)MTOK * DDIM;         // MPATCH*512 fp32 patch-embed out
    float* CLS    = EMB + (size_t)MPATCH * DDIM;     // 320*512
    float* LOGITS = CLS + (size_t)BBATCH * NLAYER * DDIM;
    float* CE     = LOGITS + BBATCH * NLAYER * NCLASS;
    float* HSC    = CE + BBATCH * NLAYER;            // MTOK (raw halt sums)
    float* HALTS  = HSC + MTOK;
    u16* QKVb = (u16*)(HALTS + BBATCH * NLAYER + 32);// QKVROWS*1536 bf16
    u16* LNB  = QKVb + (size_t)QKVROWS * 1536;       // MPAD*512 (ln out / attn out)
    u16* HB   = LNB + (size_t)MPAD * DDIM;           // MPAD*2048
    u16* XP   = HB + (size_t)MPAD * MLPDIM;          // 6272*768
    u16* CLNB = XP + (size_t)MPATCH * PDIM;          // 384*512
    u16* wWp  = CLNB + 384 * DDIM;
    u16* wWqkv= wWp   + 512 * 768;
    u16* wWo  = wWqkv + 1536 * 512;
    u16* wW1  = wWo   + 512 * 512;
    u16* wW2  = wW1   + 2048 * 512;
    u16* wWh1 = wW2   + 512 * 2048;
    u16* wWc1 = wWh1  + 2048 * 512;

    dim3 blk(256);

    f2bf_kernel<<<dim3((512*768/4 + 255)/256), blk, 0, stream>>>(Wp, wWp, 512*768/4);
    f2bf_kernel<<<dim3((1536*512/4 + 255)/256), blk, 0, stream>>>(Wqkv, wWqkv, 1536*512/4);
    f2bf_kernel<<<dim3((512*512/4 + 255)/256), blk, 0, stream>>>(Wo, wWo, 512*512/4);
    f2bf_kernel<<<dim3((2048*512/4 + 255)/256), blk, 0, stream>>>(W1, wW1, 2048*512/4);
    f2bf_kernel<<<dim3((512*2048/4 + 255)/256), blk, 0, stream>>>(W2, wW2, 512*2048/4);
    f2bf_kernel<<<dim3((2048*512/4 + 255)/256), blk, 0, stream>>>(Wh1, wWh1, 2048*512/4);
    f2bf_kernel<<<dim3((2048*512/4 + 255)/256), blk, 0, stream>>>(Wc1, wWc1, 2048*512/4);

    patch_kernel<<<dim3(((size_t)MPATCH * PDIM + 255) / 256), blk, 0, stream>>>(x, XP);
    mgemm_kernel<0,1,0,0,0><<<dim3(DDIM/128, MPATCH/128), blk, 0, stream>>>(
        XP, wWp, bp, nullptr, (void*)EMB, MPATCH, DDIM, PDIM);
    assemble_kernel<<<dim3(((size_t)MTOK * DDIM + 255) / 256), blk, 0, stream>>>(
        EMB, clstok, pos, U);

    const int MT = (MTOK + 127) / 128;  // 50

    for (int l = 0; l < NLAYER; l++) {
        ln_kernel<<<dim3((MTOK + 3) / 4), blk, 0, stream>>>(U, ln1g, ln1b, LNB, MTOK);
        mgemm_kernel<0,0,0,1,0><<<dim3(1536/128, MT), blk, 0, stream>>>(
            LNB, wWqkv, nullptr, nullptr, (void*)QKVb, MTOK, 1536, DDIM);
        attn_mfma_kernel<<<dim3(512), blk, 0, stream>>>(QKVb, LNB);
        mgemm_kernel<0,1,1,0,0><<<dim3(DDIM/128, MT), blk, 0, stream>>>(
            LNB, wWo, bo, U, (void*)U, MTOK, DDIM, DDIM);
        ln_kernel<<<dim3((MTOK + 3) / 4), blk, 0, stream>>>(U, ln2g, ln2b, LNB, MTOK);
        mgemm_kernel<1,1,0,1,0><<<dim3(MLPDIM/128, MT), blk, 0, stream>>>(
            LNB, wW1, b1, nullptr, (void*)HB, MTOK, MLPDIM, DDIM);
        mgemm_kernel<0,1,1,0,0><<<dim3(DDIM/128, MT), blk, 0, stream>>>(
            HB, wW2, b2, U, (void*)U, MTOK, DDIM, MLPDIM);
        ln_kernel<<<dim3((MTOK + 3) / 4), blk, 0, stream>>>(U, lnhg, lnhb, LNB, MTOK);
        hipMemsetAsync(HSC, 0, MTOK * sizeof(float), stream);
        mgemm_kernel<0,1,0,0,1><<<dim3(MLPDIM/128, MT), blk, 0, stream>>>(
            LNB, wWh1, bh1, Wh2, (void*)HSC, MTOK, MLPDIM, DDIM);
        halt_mean_cls_kernel<<<dim3(BBATCH), dim3(64), 0, stream>>>(
            HSC, bh2, U, HALTS, CLS, l);
    }

    ln_kernel<<<dim3((BBATCH * NLAYER + 3) / 4), blk, 0, stream>>>(
        CLS, lncg, lncb, CLNB, BBATCH * NLAYER);
    mgemm_kernel<1,1,0,1,0><<<dim3(MLPDIM/128, 3), blk, 0, stream>>>(
        CLNB, wWc1, bc1, nullptr, (void*)HB, BBATCH * NLAYER, MLPDIM, DDIM);
    head_logits_kernel<<<dim3((BBATCH * NLAYER + 3) / 4), blk, 0, stream>>>(
        HB, Wc2, bc2, LOGITS);
    ce_kernel<<<dim3(2), blk, 0, stream>>>(LOGITS, y, CE);
    loss_kernel<<<dim3(1), dim3(64), 0, stream>>>(CE, HALTS, (float*)d_out);
}

// Round 5
// 2276.232 us; speedup vs baseline: 7.7144x; 1.0288x over previous
//
#include <hip/hip_runtime.h>
#include <math.h>

#define BBATCH 32
#define NTOK 197
#define NPATCH 196
#define PDIM 768
#define DDIM 512
#define NHEAD 8
#define DHEAD 64
#define MLPDIM 2048
#define NLAYER 10
#define NCLASS 10
#define MTOK (BBATCH*NTOK)      // 6304
#define MPAD 6400               // padded rows for MFMA A-tiles (50*128)
#define MPATCH (BBATCH*NPATCH)  // 6272
#define QKVROWS (MTOK + 16)     // QKV buffer rows incl. padding for attn tiles

typedef unsigned short u16;
typedef __attribute__((ext_vector_type(8))) short bf16x8;
typedef __attribute__((ext_vector_type(4))) float f32x4;
typedef __attribute__((ext_vector_type(8))) unsigned short ushort8;

__device__ __forceinline__ float gelu_f(float x) {
    return 0.5f * x * (1.0f + erff(x * 0.70710678118654752440f));
}
__device__ __forceinline__ float bf2f(u16 u) {
    union { unsigned int i; float f; } v; v.i = ((unsigned int)u) << 16; return v.f;
}
__device__ __forceinline__ u16 f2bf(float f) {
    union { float f; unsigned int u; } v; v.f = f;
    unsigned int r = v.u + 0x7FFFu + ((v.u >> 16) & 1u);
    return (u16)(r >> 16);
}
__device__ __forceinline__ void gload_lds16(const u16* g, u16* l) {
    __builtin_amdgcn_global_load_lds((const __attribute__((address_space(1))) void*)g,
                                     (__attribute__((address_space(3))) void*)l, 16, 0, 0);
}

// ---------------------------------------------------------------------------
// bf16 MFMA GEMM, double-buffered with COUNTED vmcnt (T4): tile t+1's 8
// global_load_lds stay in flight across both barriers while tile t computes.
//   prologue: STAGE(0)
//   loop t:   STAGE(t+1); vmcnt(8); barrier; COMPUTE(t); barrier; swap
//   epilogue: vmcnt(0); barrier; COMPUTE(last)
// T1: bijective XCD swizzle on linearized block index (m204 formula).
// ---------------------------------------------------------------------------
template<int ACT, int HASB, int HASR, int OUTBF, int HALT>
__global__ __launch_bounds__(256)
void mgemm_kernel(const u16* __restrict__ A, const u16* __restrict__ W,
                  const float* __restrict__ bias, const float* __restrict__ res,
                  void* __restrict__ Cout, int M, int Nn, int K)
{
    __shared__ u16 As[2][128 * 64];
    __shared__ u16 Bs[2][128 * 64];
    const int tid = threadIdx.x;
    const int lane = tid & 63;
    const int wid = tid >> 6;
    const int wr = wid >> 1, wc = wid & 1;

    // ---- T1: bijective XCD-aware swizzle of the block index ----
    const int gx = gridDim.x;
    const int nwg = gx * gridDim.y;
    const int wg = blockIdx.y * gx + blockIdx.x;
    const int q = nwg >> 3, r = nwg & 7;
    const int xcd = wg & 7, idx = wg >> 3;
    const int swz = (xcd < r) ? xcd * (q + 1) + idx
                              : r * (q + 1) + (xcd - r) * q + idx;
    const int m0 = (swz / gx) * 128, n0 = (swz % gx) * 128;

    f32x4 acc[4][4] = {};

    const int srow = tid >> 3;
    const int dcb  = (tid & 7) << 4;

    auto stage = [&](int buf, int k0) {
        #pragma unroll
        for (int p = 0; p < 4; ++p) {
            int rr = p * 32 + srow;
            int scb = dcb ^ ((rr & 7) << 4);
            gload_lds16(A + (size_t)(m0 + rr) * K + k0 + (scb >> 1), &As[buf][p * 2048 + tid * 8]);
            gload_lds16(W + (size_t)(n0 + rr) * K + k0 + (scb >> 1), &Bs[buf][p * 2048 + tid * 8]);
        }
    };
    auto compute = [&](int buf) {
        #pragma unroll
        for (int kk = 0; kk < 64; kk += 32) {
            const int kb = (kk + ((lane >> 4) << 3)) << 1;
            bf16x8 af[4], bfr[4];
            #pragma unroll
            for (int mi = 0; mi < 4; ++mi) {
                int ar = wr * 64 + mi * 16 + (lane & 15);
                af[mi] = *(const bf16x8*)&As[buf][ar * 64 + ((kb ^ ((ar & 7) << 4)) >> 1)];
            }
            #pragma unroll
            for (int ni = 0; ni < 4; ++ni) {
                int br = wc * 64 + ni * 16 + (lane & 15);
                bfr[ni] = *(const bf16x8*)&Bs[buf][br * 64 + ((kb ^ ((br & 7) << 4)) >> 1)];
            }
            #pragma unroll
            for (int mi = 0; mi < 4; ++mi)
                #pragma unroll
                for (int ni = 0; ni < 4; ++ni)
                    acc[mi][ni] = __builtin_amdgcn_mfma_f32_16x16x32_bf16(
                        af[mi], bfr[ni], acc[mi][ni], 0, 0, 0);
        }
    };

    const int NT = K >> 6;
    stage(0, 0);
    int cur = 0;
    #pragma unroll 1
    for (int t = 0; t < NT - 1; ++t) {
        stage(cur ^ 1, (t + 1) << 6);
        asm volatile("s_waitcnt vmcnt(8)" ::: "memory");   // tile t's loads done
        __builtin_amdgcn_s_barrier();                       // buffer cur complete for all waves
        compute(cur);
        __builtin_amdgcn_s_barrier();                       // all waves done reading cur
        cur ^= 1;
    }
    asm volatile("s_waitcnt vmcnt(0)" ::: "memory");
    __builtin_amdgcn_s_barrier();
    compute(cur);

    if (HALT) {
        // halt head: per-row partial = sum_cols gelu(acc+bias)*Wh2[col]
        const float* Wh2v = res;
        float* hout = (float*)Cout;
        #pragma unroll
        for (int mi = 0; mi < 4; ++mi) {
            #pragma unroll
            for (int j = 0; j < 4; ++j) {
                int row = m0 + wr * 64 + mi * 16 + ((lane >> 4) << 2) + j;
                float part = 0.0f;
                #pragma unroll
                for (int ni = 0; ni < 4; ++ni) {
                    int col = n0 + wc * 64 + ni * 16 + (lane & 15);
                    float v = gelu_f(acc[mi][ni][j] + bias[col]);
                    part += v * Wh2v[col];
                }
                #pragma unroll
                for (int off = 1; off < 16; off <<= 1) part += __shfl_xor(part, off, 64);
                if ((lane & 15) == 0 && row < M) atomicAdd(&hout[row], part);
            }
        }
        return;
    }

    float* outf = (float*)Cout;
    u16*   outb = (u16*)Cout;
    #pragma unroll
    for (int mi = 0; mi < 4; ++mi) {
        #pragma unroll
        for (int j = 0; j < 4; ++j) {
            int row = m0 + wr * 64 + mi * 16 + ((lane >> 4) << 2) + j;
            if (row >= M) continue;
            #pragma unroll
            for (int ni = 0; ni < 4; ++ni) {
                int col = n0 + wc * 64 + ni * 16 + (lane & 15);
                float v = acc[mi][ni][j];
                if (HASB) v += bias[col];
                if (ACT)  v = gelu_f(v);
                if (HASR) v += res[(size_t)row * Nn + col];
                if (OUTBF) outb[(size_t)row * Nn + col] = f2bf(v);
                else       outf[(size_t)row * Nn + col] = v;
            }
        }
    }
}

__global__ __launch_bounds__(256)
void f2bf_kernel(const float* __restrict__ in, u16* __restrict__ out, int n4)
{
    int i = blockIdx.x * 256 + threadIdx.x;
    if (i >= n4) return;
    float4 v = ((const float4*)in)[i];
    u16 o0 = f2bf(v.x), o1 = f2bf(v.y), o2 = f2bf(v.z), o3 = f2bf(v.w);
    out[i * 4 + 0] = o0; out[i * 4 + 1] = o1; out[i * 4 + 2] = o2; out[i * 4 + 3] = o3;
}

__global__ __launch_bounds__(256)
void ln_kernel(const float* __restrict__ X, const float* __restrict__ g,
               const float* __restrict__ bb, u16* __restrict__ Y, int M)
{
    int wave = (blockIdx.x * 4) + (threadIdx.x >> 6);
    int lane = threadIdx.x & 63;
    if (wave >= M) return;
    const float* x = X + (size_t)wave * DDIM;
    float v[8];
    float s = 0.0f;
    #pragma unroll
    for (int i = 0; i < 8; i++) { v[i] = x[lane + i * 64]; s += v[i]; }
    #pragma unroll
    for (int off = 32; off; off >>= 1) s += __shfl_xor(s, off, 64);
    float mu = s * (1.0f / 512.0f);
    float q = 0.0f;
    #pragma unroll
    for (int i = 0; i < 8; i++) { float d = v[i] - mu; q += d * d; }
    #pragma unroll
    for (int off = 32; off; off >>= 1) q += __shfl_xor(q, off, 64);
    float inv = 1.0f / sqrtf(q * (1.0f / 512.0f) + 1e-5f);
    u16* y = Y + (size_t)wave * DDIM;
    #pragma unroll
    for (int i = 0; i < 8; i++) {
        int c = lane + i * 64;
        y[c] = f2bf((v[i] - mu) * inv * g[c] + bb[c]);
    }
}

__global__ __launch_bounds__(256)
void patch_kernel(const float* __restrict__ x, u16* __restrict__ xp)
{
    size_t idx = (size_t)blockIdx.x * 256 + threadIdx.x;
    if (idx >= (size_t)MPATCH * PDIM) return;
    int pd = (int)(idx % PDIM);
    int bn = (int)(idx / PDIM);
    int n = bn % NPATCH, b = bn / NPATCH;
    int c = pd % 3, pix = pd / 3;
    int px = pix % 16, py = pix / 16;
    int hx = n % 14, hy = n / 14;
    int row = hy * 16 + py, col = hx * 16 + px;
    xp[idx] = f2bf(x[((size_t)(b * 3 + c) * 224 + row) * 224 + col]);
}

__global__ __launch_bounds__(256)
void assemble_kernel(const float* __restrict__ e, const float* __restrict__ clstok,
                     const float* __restrict__ pos, float* __restrict__ U)
{
    size_t idx = (size_t)blockIdx.x * 256 + threadIdx.x;
    if (idx >= (size_t)MTOK * DDIM) return;
    int d = (int)(idx % DDIM);
    int bt = (int)(idx / DDIM);
    int t = bt % NTOK, b = bt / NTOK;
    float v = (t == 0) ? clstok[d] : e[((size_t)b * NPATCH + (t - 1)) * DDIM + d];
    U[idx] = v + pos[t * DDIM + d];
}

// ---------------------------------------------------------------------------
// MFMA attention. Grid 512: 2 blocks per (b,h).
// ---------------------------------------------------------------------------
__global__ __launch_bounds__(256)
void attn_mfma_kernel(const u16* __restrict__ qkv, u16* __restrict__ O)
{
    __shared__ u16 Ks[208 * 64];
    __shared__ u16 Vt[64 * 208];
    __shared__ u16 Pl[4 * 16 * 208];

    const int bh = blockIdx.x >> 1;
    const int half = blockIdx.x & 1;
    const int b = bh >> 3, h = bh & 7;
    const int tid = threadIdx.x;
    const int lane = tid & 63, wid = tid >> 6;
    const size_t base = ((size_t)b * NTOK) * 1536 + (size_t)h * 64;

    {
        int j0 = tid >> 3;
        int d0 = (tid & 7) * 8;
        for (int p = 0; p < 7; ++p) {
            int j = p * 32 + j0;
            if (j < 208) {
                bf16x8 v = {};
                if (j < NTOK) v = *(const bf16x8*)&qkv[base + (size_t)j * 1536 + 512 + d0];
                int byt = (j * 128 + d0 * 2) ^ ((j & 7) << 4);
                *(bf16x8*)((char*)Ks + byt) = v;
            }
        }
    }
    {
        int d = tid & 63;
        int jg = tid >> 6;
        for (int j = jg * 52; j < jg * 52 + 52; ++j) {
            u16 v = (j < NTOK) ? qkv[base + (size_t)j * 1536 + 1024 + d] : (u16)0;
            int byt = (d * 416 + j * 2) ^ ((d & 7) << 4);
            *(u16*)((char*)Vt + byt) = v;
        }
    }
    __syncthreads();

    u16* Pw = Pl + wid * 16 * 208;
    const float scale = 0.04419417382415922f;
    const int t0   = half ? 7 : 0;
    const int tcnt = half ? 6 : 7;
    const int g = lane >> 4;
    const int mycol = lane & 15;

    for (int ti = wid; ti < tcnt; ti += 4) {
        const int r0 = (t0 + ti) * 16;
        bf16x8 qf[2];
        #pragma unroll
        for (int ks = 0; ks < 2; ++ks) {
            int row = r0 + mycol;
            int col = ks * 32 + (g << 3);
            qf[ks] = *(const bf16x8*)&qkv[base + (size_t)row * 1536 + col];
        }
        f32x4 s[13];
        #pragma unroll
        for (int ct = 0; ct < 13; ++ct) s[ct] = (f32x4){0.f, 0.f, 0.f, 0.f};
        #pragma unroll
        for (int ks = 0; ks < 2; ++ks) {
            int kbyte = (ks * 32 + (g << 3)) * 2;
            #pragma unroll
            for (int ct = 0; ct < 13; ++ct) {
                int n = ct * 16 + mycol;
                bf16x8 kf = *(const bf16x8*)((char*)Ks + ((n * 128 + kbyte) ^ ((n & 7) << 4)));
                s[ct] = __builtin_amdgcn_mfma_f32_16x16x32_bf16(qf[ks], kf, s[ct], 0, 0, 0);
            }
        }
        float m[4], sum[4];
        #pragma unroll
        for (int j = 0; j < 4; ++j) m[j] = -1e30f;
        #pragma unroll
        for (int ct = 0; ct < 13; ++ct) {
            bool valid = (ct * 16 + mycol) < NTOK;
            #pragma unroll
            for (int j = 0; j < 4; ++j) {
                float v = valid ? s[ct][j] * scale : -1e30f;
                s[ct][j] = v;
                m[j] = fmaxf(m[j], v);
            }
        }
        #pragma unroll
        for (int off = 1; off < 16; off <<= 1)
            #pragma unroll
            for (int j = 0; j < 4; ++j) m[j] = fmaxf(m[j], __shfl_xor(m[j], off, 64));
        #pragma unroll
        for (int j = 0; j < 4; ++j) sum[j] = 0.0f;
        #pragma unroll
        for (int ct = 0; ct < 13; ++ct)
            #pragma unroll
            for (int j = 0; j < 4; ++j) {
                float e = expf(s[ct][j] - m[j]);
                s[ct][j] = e;
                sum[j] += e;
            }
        #pragma unroll
        for (int off = 1; off < 16; off <<= 1)
            #pragma unroll
            for (int j = 0; j < 4; ++j) sum[j] += __shfl_xor(sum[j], off, 64);
        float inv[4];
        #pragma unroll
        for (int j = 0; j < 4; ++j) inv[j] = 1.0f / sum[j];
        #pragma unroll
        for (int ct = 0; ct < 13; ++ct) {
            int col = ct * 16 + mycol;
            #pragma unroll
            for (int j = 0; j < 4; ++j) {
                int row = (g << 2) + j;
                int byt = (row * 416 + col * 2) ^ ((row & 7) << 4);
                *(u16*)((char*)Pw + byt) = f2bf(s[ct][j] * inv[j]);
            }
        }
        #pragma unroll
        for (int nt = 0; nt < 4; ++nt) {
            f32x4 o = (f32x4){0.f, 0.f, 0.f, 0.f};
            #pragma unroll
            for (int ks = 0; ks < 7; ++ks) {
                bf16x8 pf = {}, vf = {};
                bool live = !(ks == 6 && g >= 2);
                if (live) {
                    int kbyte = (ks * 32 + (g << 3)) * 2;
                    pf = *(const bf16x8*)((char*)Pw + ((mycol * 416 + kbyte) ^ ((mycol & 7) << 4)));
                    int vrow = nt * 16 + mycol;
                    vf = *(const bf16x8*)((char*)Vt + ((vrow * 416 + kbyte) ^ ((vrow & 7) << 4)));
                }
                o = __builtin_amdgcn_mfma_f32_16x16x32_bf16(pf, vf, o, 0, 0, 0);
            }
            #pragma unroll
            for (int j = 0; j < 4; ++j) {
                int grow = r0 + (g << 2) + j;
                if (grow < NTOK)
                    O[((size_t)b * NTOK + grow) * DDIM + h * 64 + nt * 16 + mycol] = f2bf(o[j]);
            }
        }
    }
}

// halts[b][l] = mean_t sigmoid(hsc_raw + bh2);  cls[b][l][:] = U[b*197+0][:]
__global__ __launch_bounds__(64)
void halt_mean_cls_kernel(const float* __restrict__ hsc, const float* __restrict__ bh2,
                          const float* __restrict__ U,
                          float* __restrict__ halts, float* __restrict__ cls, int l)
{
    int b = blockIdx.x, lane = threadIdx.x;
    float bb = bh2[0];
    float s = 0.0f;
    for (int t = lane; t < NTOK; t += 64) {
        float raw = hsc[b * NTOK + t] + bb;
        s += 1.0f / (1.0f + expf(-raw));
    }
    #pragma unroll
    for (int off = 32; off; off >>= 1) s += __shfl_xor(s, off, 64);
    if (lane == 0) halts[b * NLAYER + l] = s * (1.0f / (float)NTOK);
    for (int d = lane; d < DDIM; d += 64)
        cls[((size_t)b * NLAYER + l) * DDIM + d] = U[(size_t)b * NTOK * DDIM + d];
}

__global__ __launch_bounds__(256)
void head_logits_kernel(const u16* __restrict__ Hh, const float* __restrict__ Wc2,
                        const float* __restrict__ bc2, float* __restrict__ logits)
{
    int wave = (blockIdx.x * 4) + (threadIdx.x >> 6);
    int lane = threadIdx.x & 63;
    if (wave >= BBATCH * NLAYER) return;
    const u16* row = Hh + (size_t)wave * MLPDIM;
    float rv[32];
    #pragma unroll
    for (int i = 0; i < 32; i++) rv[i] = bf2f(row[lane + i * 64]);
    #pragma unroll
    for (int c = 0; c < NCLASS; c++) {
        float s = 0.0f;
        #pragma unroll
        for (int i = 0; i < 32; i++) s = fmaf(rv[i], Wc2[c * MLPDIM + lane + i * 64], s);
        #pragma unroll
        for (int off = 32; off; off >>= 1) s += __shfl_xor(s, off, 64);
        if (lane == 0) logits[wave * NCLASS + c] = s + bc2[c];
    }
}

__global__ __launch_bounds__(256)
void ce_kernel(const float* __restrict__ logits, const int* __restrict__ y,
               float* __restrict__ ce)
{
    int r = blockIdx.x * 256 + threadIdx.x;
    if (r >= BBATCH * NLAYER) return;
    const float* lg = logits + (size_t)r * NCLASS;
    float mx = lg[0];
    #pragma unroll
    for (int i = 1; i < NCLASS; i++) mx = fmaxf(mx, lg[i]);
    float s = 0.0f;
    #pragma unroll
    for (int i = 0; i < NCLASS; i++) s += expf(lg[i] - mx);
    int lab = y[r / NLAYER];
    ce[r] = -(lg[lab] - mx - logf(s));
}

__global__ __launch_bounds__(64)
void loss_kernel(const float* __restrict__ ce, const float* __restrict__ halts,
                 float* __restrict__ out)
{
    int b = threadIdx.x;
    float total = 0.0f;
    if (b < BBATCH) {
        const float* c = ce + b * NLAYER;
        int idx = 0; float mn = c[0];
        for (int l = 1; l < NLAYER; l++) if (c[l] < mn) { mn = c[l]; idx = l; }
        idx += 1;
        float acc = 0.0f;
        for (int l = 0; l < idx; l++) {
            acc += c[l];
            float p = halts[b * NLAYER + l];
            p = fminf(fmaxf(p, 1e-7f), 1.0f - 1e-7f);
            float hl = (l == idx - 1) ? 0.0f : 1.0f;
            acc += -(hl * logf(p) + (1.0f - hl) * log1pf(-p));
        }
        total = acc / (float)idx;
    }
    #pragma unroll
    for (int off = 32; off; off >>= 1) total += __shfl_xor(total, off, 64);
    if (threadIdx.x == 0) out[0] = total * (1.0f / (float)BBATCH);
}

extern "C" void kernel_launch(void* const* d_in, const int* in_sizes, int n_in,
                              void* d_out, int out_size, void* d_ws, size_t ws_size,
                              hipStream_t stream)
{
    const float* x      = (const float*)d_in[0];
    const int*   y      = (const int*)d_in[1];
    const float* pos    = (const float*)d_in[2];
    const float* clstok = (const float*)d_in[3];
    const float* Wp     = (const float*)d_in[4];
    const float* bp     = (const float*)d_in[5];
    const float* Wqkv   = (const float*)d_in[6];
    const float* Wo     = (const float*)d_in[7];
    const float* bo     = (const float*)d_in[8];
    const float* ln1g   = (const float*)d_in[9];
    const float* ln1b   = (const float*)d_in[10];
    const float* ln2g   = (const float*)d_in[11];
    const float* ln2b   = (const float*)d_in[12];
    const float* W1     = (const float*)d_in[13];
    const float* b1     = (const float*)d_in[14];
    const float* W2     = (const float*)d_in[15];
    const float* b2     = (const float*)d_in[16];
    const float* lnhg   = (const float*)d_in[17];
    const float* lnhb   = (const float*)d_in[18];
    const float* Wh1    = (const float*)d_in[19];
    const float* bh1    = (const float*)d_in[20];
    const float* Wh2    = (const float*)d_in[21];
    const float* bh2    = (const float*)d_in[22];
    const float* lncg   = (const float*)d_in[23];
    const float* lncb   = (const float*)d_in[24];
    const float* Wc1    = (const float*)d_in[25];
    const float* bc1    = (const float*)d_in[26];
    const float* Wc2    = (const float*)d_in[27];
    const float* bc2    = (const float*)d_in[28];

    // ---- workspace layout ----
    float* U      = (float*)d_ws;                    // MTOK*512
    float* EMB    = U + (size_t)MTOK * DDIM;         // MPATCH*512 fp32 patch-embed out
    float* CLS    = EMB + (size_t)MPATCH * DDIM;     // 320*512
    float* LOGITS = CLS + (size_t)BBATCH * NLAYER * DDIM;
    float* CE     = LOGITS + BBATCH * NLAYER * NCLASS;
    float* HSC    = CE + BBATCH * NLAYER;            // MTOK (raw halt sums)
    float* HALTS  = HSC + MTOK;
    u16* QKVb = (u16*)(HALTS + BBATCH * NLAYER + 32);// QKVROWS*1536 bf16
    u16* LNB  = QKVb + (size_t)QKVROWS * 1536;       // MPAD*512 (ln out / attn out)
    u16* HB   = LNB + (size_t)MPAD * DDIM;           // MPAD*2048
    u16* XP   = HB + (size_t)MPAD * MLPDIM;          // 6272*768
    u16* CLNB = XP + (size_t)MPATCH * PDIM;          // 384*512
    u16* wWp  = CLNB + 384 * DDIM;
    u16* wWqkv= wWp   + 512 * 768;
    u16* wWo  = wWqkv + 1536 * 512;
    u16* wW1  = wWo   + 512 * 512;
    u16* wW2  = wW1   + 2048 * 512;
    u16* wWh1 = wW2   + 512 * 2048;
    u16* wWc1 = wWh1  + 2048 * 512;

    dim3 blk(256);

    f2bf_kernel<<<dim3((512*768/4 + 255)/256), blk, 0, stream>>>(Wp, wWp, 512*768/4);
    f2bf_kernel<<<dim3((1536*512/4 + 255)/256), blk, 0, stream>>>(Wqkv, wWqkv, 1536*512/4);
    f2bf_kernel<<<dim3((512*512/4 + 255)/256), blk, 0, stream>>>(Wo, wWo, 512*512/4);
    f2bf_kernel<<<dim3((2048*512/4 + 255)/256), blk, 0, stream>>>(W1, wW1, 2048*512/4);
    f2bf_kernel<<<dim3((512*2048/4 + 255)/256), blk, 0, stream>>>(W2, wW2, 512*2048/4);
    f2bf_kernel<<<dim3((2048*512/4 + 255)/256), blk, 0, stream>>>(Wh1, wWh1, 2048*512/4);
    f2bf_kernel<<<dim3((2048*512/4 + 255)/256), blk, 0, stream>>>(Wc1, wWc1, 2048*512/4);

    patch_kernel<<<dim3(((size_t)MPATCH * PDIM + 255) / 256), blk, 0, stream>>>(x, XP);
    mgemm_kernel<0,1,0,0,0><<<dim3(DDIM/128, MPATCH/128), blk, 0, stream>>>(
        XP, wWp, bp, nullptr, (void*)EMB, MPATCH, DDIM, PDIM);
    assemble_kernel<<<dim3(((size_t)MTOK * DDIM + 255) / 256), blk, 0, stream>>>(
        EMB, clstok, pos, U);

    const int MT = (MTOK + 127) / 128;  // 50

    for (int l = 0; l < NLAYER; l++) {
        ln_kernel<<<dim3((MTOK + 3) / 4), blk, 0, stream>>>(U, ln1g, ln1b, LNB, MTOK);
        mgemm_kernel<0,0,0,1,0><<<dim3(1536/128, MT), blk, 0, stream>>>(
            LNB, wWqkv, nullptr, nullptr, (void*)QKVb, MTOK, 1536, DDIM);
        attn_mfma_kernel<<<dim3(512), blk, 0, stream>>>(QKVb, LNB);
        mgemm_kernel<0,1,1,0,0><<<dim3(DDIM/128, MT), blk, 0, stream>>>(
            LNB, wWo, bo, U, (void*)U, MTOK, DDIM, DDIM);
        ln_kernel<<<dim3((MTOK + 3) / 4), blk, 0, stream>>>(U, ln2g, ln2b, LNB, MTOK);
        mgemm_kernel<1,1,0,1,0><<<dim3(MLPDIM/128, MT), blk, 0, stream>>>(
            LNB, wW1, b1, nullptr, (void*)HB, MTOK, MLPDIM, DDIM);
        mgemm_kernel<0,1,1,0,0><<<dim3(DDIM/128, MT), blk, 0, stream>>>(
            HB, wW2, b2, U, (void*)U, MTOK, DDIM, MLPDIM);
        ln_kernel<<<dim3((MTOK + 3) / 4), blk, 0, stream>>>(U, lnhg, lnhb, LNB, MTOK);
        hipMemsetAsync(HSC, 0, MTOK * sizeof(float), stream);
        mgemm_kernel<0,1,0,0,1><<<dim3(MLPDIM/128, MT), blk, 0, stream>>>(
            LNB, wWh1, bh1, Wh2, (void*)HSC, MTOK, MLPDIM, DDIM);
        halt_mean_cls_kernel<<<dim3(BBATCH), dim3(64), 0, stream>>>(
            HSC, bh2, U, HALTS, CLS, l);
    }

    ln_kernel<<<dim3((BBATCH * NLAYER + 3) / 4), blk, 0, stream>>>(
        CLS, lncg, lncb, CLNB, BBATCH * NLAYER);
    mgemm_kernel<1,1,0,1,0><<<dim3(MLPDIM/128, 3), blk, 0, stream>>>(
        CLNB, wWc1, bc1, nullptr, (void*)HB, BBATCH * NLAYER, MLPDIM, DDIM);
    head_logits_kernel<<<dim3((BBATCH * NLAYER + 3) / 4), blk, 0, stream>>>(
        HB, Wc2, bc2, LOGITS);
    ce_kernel<<<dim3(2), blk, 0, stream>>>(LOGITS, y, CE);
    loss_kernel<<<dim3(1), dim3(64), 0, stream>>>(CE, HALTS, (float*)d_out);
}

// Round 6
// 2251.419 us; speedup vs baseline: 7.7995x; 1.0110x over previous
//
#include <hip/hip_runtime.h>
#include <math.h>

#define BBATCH 32
#define NTOK 197
#define NPATCH 196
#define PDIM 768
#define DDIM 512
#define NHEAD 8
#define DHEAD 64
#define MLPDIM 2048
#define NLAYER 10
#define NCLASS 10
#define MTOK (BBATCH*NTOK)      // 6304
#define MPAD 6400               // padded rows (25*256)
#define MPATCH (BBATCH*NPATCH)  // 6272
#define QKVROWS (MTOK + 16)

typedef unsigned short u16;
typedef __attribute__((ext_vector_type(8))) short bf16x8;
typedef __attribute__((ext_vector_type(4))) float f32x4;

__device__ __forceinline__ float gelu_f(float x) {
    return 0.5f * x * (1.0f + erff(x * 0.70710678118654752440f));
}
__device__ __forceinline__ float bf2f(u16 u) {
    union { unsigned int i; float f; } v; v.i = ((unsigned int)u) << 16; return v.f;
}
__device__ __forceinline__ u16 f2bf(float f) {
    union { float f; unsigned int u; } v; v.f = f;
    unsigned int r = v.u + 0x7FFFu + ((v.u >> 16) & 1u);
    return (u16)(r >> 16);
}
__device__ __forceinline__ void gload_lds16(const u16* g, u16* l) {
    __builtin_amdgcn_global_load_lds((const __attribute__((address_space(1))) void*)g,
                                     (__attribute__((address_space(3))) void*)l, 16, 0, 0);
}
__device__ __forceinline__ int swz_bij(int wg, int nwg) {
    int q = nwg >> 3, r = nwg & 7, xcd = wg & 7, id8 = wg >> 3;
    return (xcd < r) ? xcd * (q + 1) + id8 : r * (q + 1) + (xcd - r) * q + id8;
}

// ---------------------------------------------------------------------------
// 256x128-tile bf16 MFMA GEMM (K=512 fixed), 512 thr = 8 waves (4M x 2N),
// per-wave 64x64 (proven micro-kernel). Double-buffered, counted vmcnt(6).
// Two block-modes per dispatch: blocks [0,nA) run MODEA on param-set a,
// the rest MODEB on param-set b.  Modes: 0 = bf16 out (no bias/act),
// 1 = halt (gelu(acc+bias).wh2 -> atomicAdd per-row), 2 = bias+gelu bf16 out.
// ---------------------------------------------------------------------------
template<int MODEA, int MODEB>
__global__ __launch_bounds__(512)
void gemm256_kernel(int nA, int colsA, int colsB,
                    const u16* __restrict__ Aa, const u16* __restrict__ Wa,
                    const float* __restrict__ biasa, void* __restrict__ outa, int Na,
                    const u16* __restrict__ Ab, const u16* __restrict__ Wb,
                    const float* __restrict__ biasb, const float* __restrict__ wh2,
                    void* __restrict__ outb, int Nb, int M)
{
    __shared__ u16 As[2][256 * 64];
    __shared__ u16 Bs[2][128 * 64];
    const int tid = threadIdx.x, lane = tid & 63, wid = tid >> 6;
    const int wr = wid >> 1, wc = wid & 1;

    const int swz = swz_bij(blockIdx.x, gridDim.x);
    int mode, m0, n0, Nn;
    const u16 *A, *W; const float* bias; void* out;
    if (swz < nA) {
        mode = MODEA; A = Aa; W = Wa; bias = biasa; out = outa; Nn = Na;
        m0 = (swz / colsA) * 256; n0 = (swz % colsA) * 128;
    } else {
        int s2 = swz - nA;
        mode = MODEB; A = Ab; W = Wb; bias = biasb; out = outb; Nn = Nb;
        m0 = (s2 / colsB) * 256; n0 = (s2 % colsB) * 128;
    }

    f32x4 acc[4][4] = {};
    const int srow = tid >> 3;          // 0..63
    const int dcb  = (tid & 7) << 4;

    auto stage = [&](int buf, int k0) {
        #pragma unroll
        for (int p = 0; p < 4; ++p) {
            int rr = p * 64 + srow;
            int scb = dcb ^ ((rr & 7) << 4);
            gload_lds16(A + (size_t)(m0 + rr) * 512 + k0 + (scb >> 1), &As[buf][p * 4096 + tid * 8]);
        }
        #pragma unroll
        for (int p = 0; p < 2; ++p) {
            int rr = p * 64 + srow;
            int scb = dcb ^ ((rr & 7) << 4);
            gload_lds16(W + (size_t)(n0 + rr) * 512 + k0 + (scb >> 1), &Bs[buf][p * 4096 + tid * 8]);
        }
    };
    auto compute = [&](int buf) {
        #pragma unroll
        for (int kk = 0; kk < 64; kk += 32) {
            const int kb = (kk + ((lane >> 4) << 3)) << 1;
            bf16x8 af[4], bfr[4];
            #pragma unroll
            for (int mi = 0; mi < 4; ++mi) {
                int ar = wr * 64 + mi * 16 + (lane & 15);
                af[mi] = *(const bf16x8*)&As[buf][ar * 64 + ((kb ^ ((ar & 7) << 4)) >> 1)];
            }
            #pragma unroll
            for (int ni = 0; ni < 4; ++ni) {
                int br = wc * 64 + ni * 16 + (lane & 15);
                bfr[ni] = *(const bf16x8*)&Bs[buf][br * 64 + ((kb ^ ((br & 7) << 4)) >> 1)];
            }
            #pragma unroll
            for (int mi = 0; mi < 4; ++mi)
                #pragma unroll
                for (int ni = 0; ni < 4; ++ni)
                    acc[mi][ni] = __builtin_amdgcn_mfma_f32_16x16x32_bf16(
                        af[mi], bfr[ni], acc[mi][ni], 0, 0, 0);
        }
    };

    stage(0, 0);
    int cur = 0;
    #pragma unroll 1
    for (int t = 0; t < 7; ++t) {               // K=512 -> 8 tiles
        stage(cur ^ 1, (t + 1) << 6);
        asm volatile("s_waitcnt vmcnt(6)" ::: "memory");
        __builtin_amdgcn_s_barrier();
        compute(cur);
        __builtin_amdgcn_s_barrier();
        cur ^= 1;
    }
    asm volatile("s_waitcnt vmcnt(0)" ::: "memory");
    __builtin_amdgcn_s_barrier();
    compute(cur);

    if (mode == 1) {
        float* hout = (float*)out;
        #pragma unroll
        for (int mi = 0; mi < 4; ++mi) {
            #pragma unroll
            for (int j = 0; j < 4; ++j) {
                int row = m0 + wr * 64 + mi * 16 + ((lane >> 4) << 2) + j;
                float part = 0.0f;
                #pragma unroll
                for (int ni = 0; ni < 4; ++ni) {
                    int col = n0 + wc * 64 + ni * 16 + (lane & 15);
                    part += gelu_f(acc[mi][ni][j] + bias[col]) * wh2[col];
                }
                #pragma unroll
                for (int off = 1; off < 16; off <<= 1) part += __shfl_xor(part, off, 64);
                if ((lane & 15) == 0 && row < M) atomicAdd(&hout[row], part);
            }
        }
        return;
    }
    u16* outb16 = (u16*)out;
    #pragma unroll
    for (int mi = 0; mi < 4; ++mi) {
        #pragma unroll
        for (int j = 0; j < 4; ++j) {
            int row = m0 + wr * 64 + mi * 16 + ((lane >> 4) << 2) + j;
            if (row >= M) continue;
            #pragma unroll
            for (int ni = 0; ni < 4; ++ni) {
                int col = n0 + wc * 64 + ni * 16 + (lane & 15);
                float v = acc[mi][ni][j];
                if (mode == 2) v = gelu_f(v + bias[col]);
                outb16[(size_t)row * Nn + col] = f2bf(v);
            }
        }
    }
}

// ---------------------------------------------------------------------------
// 128x128 bf16 MFMA GEMM with optional split-K (ATOMIC accumulate into fp32).
// gridDim.y = mtiles * nsplit; kbase = ks*kcount.
// ---------------------------------------------------------------------------
template<int ACT, int HASB, int HASR, int OUTBF, int ATOMIC>
__global__ __launch_bounds__(256)
void mgemm_kernel(const u16* __restrict__ A, const u16* __restrict__ W,
                  const float* __restrict__ bias, const float* __restrict__ res,
                  void* __restrict__ Cout, int M, int Nn, int K, int kcount, int mtiles)
{
    __shared__ u16 As[2][128 * 64];
    __shared__ u16 Bs[2][128 * 64];
    const int tid = threadIdx.x, lane = tid & 63, wid = tid >> 6;
    const int wr = wid >> 1, wc = wid & 1;

    const int gx = gridDim.x;
    const int swz = swz_bij(blockIdx.y * gx + blockIdx.x, gx * gridDim.y);
    const int ry = swz / gx;
    const int ks = ry / mtiles;
    const int m0 = (ry % mtiles) * 128, n0 = (swz % gx) * 128;
    const int kbase = ks * kcount;

    f32x4 acc[4][4] = {};
    const int srow = tid >> 3;
    const int dcb  = (tid & 7) << 4;

    auto stage = [&](int buf, int k0) {
        #pragma unroll
        for (int p = 0; p < 4; ++p) {
            int rr = p * 32 + srow;
            int scb = dcb ^ ((rr & 7) << 4);
            gload_lds16(A + (size_t)(m0 + rr) * K + k0 + (scb >> 1), &As[buf][p * 2048 + tid * 8]);
            gload_lds16(W + (size_t)(n0 + rr) * K + k0 + (scb >> 1), &Bs[buf][p * 2048 + tid * 8]);
        }
    };
    auto compute = [&](int buf) {
        #pragma unroll
        for (int kk = 0; kk < 64; kk += 32) {
            const int kb = (kk + ((lane >> 4) << 3)) << 1;
            bf16x8 af[4], bfr[4];
            #pragma unroll
            for (int mi = 0; mi < 4; ++mi) {
                int ar = wr * 64 + mi * 16 + (lane & 15);
                af[mi] = *(const bf16x8*)&As[buf][ar * 64 + ((kb ^ ((ar & 7) << 4)) >> 1)];
            }
            #pragma unroll
            for (int ni = 0; ni < 4; ++ni) {
                int br = wc * 64 + ni * 16 + (lane & 15);
                bfr[ni] = *(const bf16x8*)&Bs[buf][br * 64 + ((kb ^ ((br & 7) << 4)) >> 1)];
            }
            #pragma unroll
            for (int mi = 0; mi < 4; ++mi)
                #pragma unroll
                for (int ni = 0; ni < 4; ++ni)
                    acc[mi][ni] = __builtin_amdgcn_mfma_f32_16x16x32_bf16(
                        af[mi], bfr[ni], acc[mi][ni], 0, 0, 0);
        }
    };

    const int NT = kcount >> 6;
    stage(0, kbase);
    int cur = 0;
    #pragma unroll 1
    for (int t = 0; t < NT - 1; ++t) {
        stage(cur ^ 1, kbase + ((t + 1) << 6));
        asm volatile("s_waitcnt vmcnt(8)" ::: "memory");
        __builtin_amdgcn_s_barrier();
        compute(cur);
        __builtin_amdgcn_s_barrier();
        cur ^= 1;
    }
    asm volatile("s_waitcnt vmcnt(0)" ::: "memory");
    __builtin_amdgcn_s_barrier();
    compute(cur);

    float* outf = (float*)Cout;
    u16*   outb = (u16*)Cout;
    #pragma unroll
    for (int mi = 0; mi < 4; ++mi) {
        #pragma unroll
        for (int j = 0; j < 4; ++j) {
            int row = m0 + wr * 64 + mi * 16 + ((lane >> 4) << 2) + j;
            if (row >= M) continue;
            #pragma unroll
            for (int ni = 0; ni < 4; ++ni) {
                int col = n0 + wc * 64 + ni * 16 + (lane & 15);
                float v = acc[mi][ni][j];
                if (ATOMIC) {
                    if (HASB && ks == 0) v += bias[col];
                    atomicAdd(&outf[(size_t)row * Nn + col], v);
                } else {
                    if (HASB) v += bias[col];
                    if (ACT)  v = gelu_f(v);
                    if (HASR) v += res[(size_t)row * Nn + col];
                    if (OUTBF) outb[(size_t)row * Nn + col] = f2bf(v);
                    else       outf[(size_t)row * Nn + col] = v;
                }
            }
        }
    }
}

// ---------------------------------------------------------------------------
// LayerNorm: one wave per row (grid-strided), fp32 in, one or two bf16 outs.
// ---------------------------------------------------------------------------
__global__ __launch_bounds__(256)
void ln_one_kernel(const float* __restrict__ X, const float* __restrict__ g,
                   const float* __restrict__ bb, u16* __restrict__ Y, int M)
{
    int w0 = blockIdx.x * 4 + (threadIdx.x >> 6);
    int lane = threadIdx.x & 63;
    int stride = gridDim.x * 4;
    for (int row = w0; row < M; row += stride) {
        const float* x = X + (size_t)row * DDIM;
        float v[8], s = 0.0f;
        #pragma unroll
        for (int i = 0; i < 8; i++) { v[i] = x[lane + i * 64]; s += v[i]; }
        #pragma unroll
        for (int off = 32; off; off >>= 1) s += __shfl_xor(s, off, 64);
        float mu = s * (1.0f / 512.0f), q = 0.0f;
        #pragma unroll
        for (int i = 0; i < 8; i++) { float d = v[i] - mu; q += d * d; }
        #pragma unroll
        for (int off = 32; off; off >>= 1) q += __shfl_xor(q, off, 64);
        float inv = 1.0f / sqrtf(q * (1.0f / 512.0f) + 1e-5f);
        u16* y = Y + (size_t)row * DDIM;
        #pragma unroll
        for (int i = 0; i < 8; i++) {
            int c = lane + i * 64;
            y[c] = f2bf((v[i] - mu) * inv * g[c] + bb[c]);
        }
    }
}

__global__ __launch_bounds__(256)
void ln_dual_kernel(const float* __restrict__ X,
                    const float* __restrict__ g1, const float* __restrict__ b1,
                    const float* __restrict__ g2, const float* __restrict__ b2,
                    u16* __restrict__ Y1, u16* __restrict__ Y2, int M)
{
    int w0 = blockIdx.x * 4 + (threadIdx.x >> 6);
    int lane = threadIdx.x & 63;
    int stride = gridDim.x * 4;
    for (int row = w0; row < M; row += stride) {
        const float* x = X + (size_t)row * DDIM;
        float v[8], s = 0.0f;
        #pragma unroll
        for (int i = 0; i < 8; i++) { v[i] = x[lane + i * 64]; s += v[i]; }
        #pragma unroll
        for (int off = 32; off; off >>= 1) s += __shfl_xor(s, off, 64);
        float mu = s * (1.0f / 512.0f), q = 0.0f;
        #pragma unroll
        for (int i = 0; i < 8; i++) { float d = v[i] - mu; q += d * d; }
        #pragma unroll
        for (int off = 32; off; off >>= 1) q += __shfl_xor(q, off, 64);
        float inv = 1.0f / sqrtf(q * (1.0f / 512.0f) + 1e-5f);
        u16* y1 = Y1 + (size_t)row * DDIM;
        u16* y2 = Y2 + (size_t)row * DDIM;
        #pragma unroll
        for (int i = 0; i < 8; i++) {
            int c = lane + i * 64;
            float n = (v[i] - mu) * inv;
            y1[c] = f2bf(n * g1[c] + b1[c]);
            y2[c] = f2bf(n * g2[c] + b2[c]);
        }
    }
}

// ---------------------------------------------------------------------------
// Patch extraction / assemble (grid-strided)
// ---------------------------------------------------------------------------
__global__ __launch_bounds__(256)
void patch_kernel(const float* __restrict__ x, u16* __restrict__ xp)
{
    const size_t total = (size_t)MPATCH * PDIM;
    for (size_t idx = (size_t)blockIdx.x * 256 + threadIdx.x; idx < total;
         idx += (size_t)gridDim.x * 256) {
        int pd = (int)(idx % PDIM);
        int bn = (int)(idx / PDIM);
        int n = bn % NPATCH, b = bn / NPATCH;
        int c = pd % 3, pix = pd / 3;
        int px = pix % 16, py = pix / 16;
        int hx = n % 14, hy = n / 14;
        int row = hy * 16 + py, col = hx * 16 + px;
        xp[idx] = f2bf(x[((size_t)(b * 3 + c) * 224 + row) * 224 + col]);
    }
}

__global__ __launch_bounds__(256)
void assemble_kernel(const float* __restrict__ e, const float* __restrict__ clstok,
                     const float* __restrict__ pos, float* __restrict__ U)
{
    const size_t total = (size_t)MTOK * DDIM;
    for (size_t idx = (size_t)blockIdx.x * 256 + threadIdx.x; idx < total;
         idx += (size_t)gridDim.x * 256) {
        int d = (int)(idx % DDIM);
        int bt = (int)(idx / DDIM);
        int t = bt % NTOK, b = bt / NTOK;
        float v = (t == 0) ? clstok[d] : e[((size_t)b * NPATCH + (t - 1)) * DDIM + d];
        U[idx] = v + pos[t * DDIM + d];
    }
}

// one kernel converting all 7 weight matrices fp32->bf16 (contiguous dst)
__global__ __launch_bounds__(256)
void convert7_kernel(const float* s0, const float* s1, const float* s2,
                     const float* s3, const float* s4, const float* s5,
                     const float* s6, u16* __restrict__ dst)
{
    const int total4 = 1409024;  // 5636096/4
    for (int i4 = blockIdx.x * 256 + threadIdx.x; i4 < total4; i4 += gridDim.x * 256) {
        size_t e = (size_t)i4 * 4;
        const float* s; size_t off;
        if      (e < 393216)  { s = s0; off = 0; }
        else if (e < 1179648) { s = s1; off = 393216; }
        else if (e < 1441792) { s = s2; off = 1179648; }
        else if (e < 2490368) { s = s3; off = 1441792; }
        else if (e < 3538944) { s = s4; off = 2490368; }
        else if (e < 4587520) { s = s5; off = 3538944; }
        else                  { s = s6; off = 4587520; }
        float4 v = ((const float4*)s)[(e - off) >> 2];
        dst[e + 0] = f2bf(v.x); dst[e + 1] = f2bf(v.y);
        dst[e + 2] = f2bf(v.z); dst[e + 3] = f2bf(v.w);
    }
}

// ---------------------------------------------------------------------------
// MFMA attention (blocks 0..511) with optional fused halt-mean (blocks 512+).
// ---------------------------------------------------------------------------
template<int HM>
__global__ __launch_bounds__(256)
void attn_hm_kernel(const u16* __restrict__ qkv, u16* __restrict__ O,
                    const float* __restrict__ hsc, const float* __restrict__ bh2,
                    const float* __restrict__ U, float* __restrict__ halts,
                    float* __restrict__ cls, int lidx)
{
    __shared__ u16 Ks[208 * 64];
    __shared__ u16 Vt[64 * 208];
    __shared__ u16 Pl[4 * 16 * 208];

    if (HM && blockIdx.x >= 512) {
        int b = blockIdx.x - 512;
        int ln = threadIdx.x;
        if (ln >= 64) return;
        float bb = bh2[0];
        float s = 0.0f;
        for (int t = ln; t < NTOK; t += 64)
            s += 1.0f / (1.0f + expf(-(hsc[b * NTOK + t] + bb)));
        #pragma unroll
        for (int off = 32; off; off >>= 1) s += __shfl_xor(s, off, 64);
        if (ln == 0) halts[b * NLAYER + lidx] = s * (1.0f / (float)NTOK);
        for (int d = ln; d < DDIM; d += 64)
            cls[((size_t)b * NLAYER + lidx) * DDIM + d] = U[(size_t)b * NTOK * DDIM + d];
        return;
    }

    const int bh = blockIdx.x >> 1;
    const int half = blockIdx.x & 1;
    const int b = bh >> 3, h = bh & 7;
    const int tid = threadIdx.x;
    const int lane = tid & 63, wid = tid >> 6;
    const size_t base = ((size_t)b * NTOK) * 1536 + (size_t)h * 64;

    {
        int j0 = tid >> 3;
        int d0 = (tid & 7) * 8;
        for (int p = 0; p < 7; ++p) {
            int j = p * 32 + j0;
            if (j < 208) {
                bf16x8 v = {};
                if (j < NTOK) v = *(const bf16x8*)&qkv[base + (size_t)j * 1536 + 512 + d0];
                int byt = (j * 128 + d0 * 2) ^ ((j & 7) << 4);
                *(bf16x8*)((char*)Ks + byt) = v;
            }
        }
    }
    {
        int d = tid & 63;
        int jg = tid >> 6;
        for (int j = jg * 52; j < jg * 52 + 52; ++j) {
            u16 v = (j < NTOK) ? qkv[base + (size_t)j * 1536 + 1024 + d] : (u16)0;
            int byt = (d * 416 + j * 2) ^ ((d & 7) << 4);
            *(u16*)((char*)Vt + byt) = v;
        }
    }
    __syncthreads();

    u16* Pw = Pl + wid * 16 * 208;
    const float scale = 0.04419417382415922f;
    const int t0   = half ? 7 : 0;
    const int tcnt = half ? 6 : 7;
    const int g = lane >> 4;
    const int mycol = lane & 15;

    for (int ti = wid; ti < tcnt; ti += 4) {
        const int r0 = (t0 + ti) * 16;
        bf16x8 qf[2];
        #pragma unroll
        for (int ks = 0; ks < 2; ++ks) {
            int row = r0 + mycol;
            int col = ks * 32 + (g << 3);
            qf[ks] = *(const bf16x8*)&qkv[base + (size_t)row * 1536 + col];
        }
        f32x4 s[13];
        #pragma unroll
        for (int ct = 0; ct < 13; ++ct) s[ct] = (f32x4){0.f, 0.f, 0.f, 0.f};
        #pragma unroll
        for (int ks = 0; ks < 2; ++ks) {
            int kbyte = (ks * 32 + (g << 3)) * 2;
            #pragma unroll
            for (int ct = 0; ct < 13; ++ct) {
                int n = ct * 16 + mycol;
                bf16x8 kf = *(const bf16x8*)((char*)Ks + ((n * 128 + kbyte) ^ ((n & 7) << 4)));
                s[ct] = __builtin_amdgcn_mfma_f32_16x16x32_bf16(qf[ks], kf, s[ct], 0, 0, 0);
            }
        }
        float m[4], sum[4];
        #pragma unroll
        for (int j = 0; j < 4; ++j) m[j] = -1e30f;
        #pragma unroll
        for (int ct = 0; ct < 13; ++ct) {
            bool valid = (ct * 16 + mycol) < NTOK;
            #pragma unroll
            for (int j = 0; j < 4; ++j) {
                float v = valid ? s[ct][j] * scale : -1e30f;
                s[ct][j] = v;
                m[j] = fmaxf(m[j], v);
            }
        }
        #pragma unroll
        for (int off = 1; off < 16; off <<= 1)
            #pragma unroll
            for (int j = 0; j < 4; ++j) m[j] = fmaxf(m[j], __shfl_xor(m[j], off, 64));
        #pragma unroll
        for (int j = 0; j < 4; ++j) sum[j] = 0.0f;
        #pragma unroll
        for (int ct = 0; ct < 13; ++ct)
            #pragma unroll
            for (int j = 0; j < 4; ++j) {
                float e = expf(s[ct][j] - m[j]);
                s[ct][j] = e;
                sum[j] += e;
            }
        #pragma unroll
        for (int off = 1; off < 16; off <<= 1)
            #pragma unroll
            for (int j = 0; j < 4; ++j) sum[j] += __shfl_xor(sum[j], off, 64);
        float inv[4];
        #pragma unroll
        for (int j = 0; j < 4; ++j) inv[j] = 1.0f / sum[j];
        #pragma unroll
        for (int ct = 0; ct < 13; ++ct) {
            int col = ct * 16 + mycol;
            #pragma unroll
            for (int j = 0; j < 4; ++j) {
                int row = (g << 2) + j;
                int byt = (row * 416 + col * 2) ^ ((row & 7) << 4);
                *(u16*)((char*)Pw + byt) = f2bf(s[ct][j] * inv[j]);
            }
        }
        #pragma unroll
        for (int nt = 0; nt < 4; ++nt) {
            f32x4 o = (f32x4){0.f, 0.f, 0.f, 0.f};
            #pragma unroll
            for (int ks = 0; ks < 7; ++ks) {
                bf16x8 pf = {}, vf = {};
                bool live = !(ks == 6 && g >= 2);
                if (live) {
                    int kbyte = (ks * 32 + (g << 3)) * 2;
                    pf = *(const bf16x8*)((char*)Pw + ((mycol * 416 + kbyte) ^ ((mycol & 7) << 4)));
                    int vrow = nt * 16 + mycol;
                    vf = *(const bf16x8*)((char*)Vt + ((vrow * 416 + kbyte) ^ ((vrow & 7) << 4)));
                }
                o = __builtin_amdgcn_mfma_f32_16x16x32_bf16(pf, vf, o, 0, 0, 0);
            }
            #pragma unroll
            for (int j = 0; j < 4; ++j) {
                int grow = r0 + (g << 2) + j;
                if (grow < NTOK)
                    O[((size_t)b * NTOK + grow) * DDIM + h * 64 + nt * 16 + mycol] = f2bf(o[j]);
            }
        }
    }
}

// standalone halt-mean for the last layer
__global__ __launch_bounds__(64)
void haltmean_kernel(const float* __restrict__ hsc, const float* __restrict__ bh2,
                     const float* __restrict__ U, float* __restrict__ halts,
                     float* __restrict__ cls, int lidx)
{
    int b = blockIdx.x, lane = threadIdx.x;
    float bb = bh2[0];
    float s = 0.0f;
    for (int t = lane; t < NTOK; t += 64)
        s += 1.0f / (1.0f + expf(-(hsc[b * NTOK + t] + bb)));
    #pragma unroll
    for (int off = 32; off; off >>= 1) s += __shfl_xor(s, off, 64);
    if (lane == 0) halts[b * NLAYER + lidx] = s * (1.0f / (float)NTOK);
    for (int d = lane; d < DDIM; d += 64)
        cls[((size_t)b * NLAYER + lidx) * DDIM + d] = U[(size_t)b * NTOK * DDIM + d];
}

__global__ __launch_bounds__(256)
void head_logits_kernel(const u16* __restrict__ Hh, const float* __restrict__ Wc2,
                        const float* __restrict__ bc2, float* __restrict__ logits)
{
    int wave = (blockIdx.x * 4) + (threadIdx.x >> 6);
    int lane = threadIdx.x & 63;
    if (wave >= BBATCH * NLAYER) return;
    const u16* row = Hh + (size_t)wave * MLPDIM;
    float rv[32];
    #pragma unroll
    for (int i = 0; i < 32; i++) rv[i] = bf2f(row[lane + i * 64]);
    #pragma unroll
    for (int c = 0; c < NCLASS; c++) {
        float s = 0.0f;
        #pragma unroll
        for (int i = 0; i < 32; i++) s = fmaf(rv[i], Wc2[c * MLPDIM + lane + i * 64], s);
        #pragma unroll
        for (int off = 32; off; off >>= 1) s += __shfl_xor(s, off, 64);
        if (lane == 0) logits[wave * NCLASS + c] = s + bc2[c];
    }
}

// fused CE + ACT loss (one block)
__global__ __launch_bounds__(256)
void celoss_kernel(const float* __restrict__ logits, const int* __restrict__ y,
                   const float* __restrict__ halts, float* __restrict__ out)
{
    __shared__ float ceS[BBATCH * NLAYER];
    __shared__ float bl[BBATCH];
    int tid = threadIdx.x;
    for (int r = tid; r < BBATCH * NLAYER; r += 256) {
        const float* lg = logits + (size_t)r * NCLASS;
        float mx = lg[0];
        #pragma unroll
        for (int i = 1; i < NCLASS; i++) mx = fmaxf(mx, lg[i]);
        float s = 0.0f;
        #pragma unroll
        for (int i = 0; i < NCLASS; i++) s += expf(lg[i] - mx);
        int lab = y[r / NLAYER];
        ceS[r] = -(lg[lab] - mx - logf(s));
    }
    __syncthreads();
    if (tid < BBATCH) {
        const float* c = ceS + tid * NLAYER;
        int idx = 0; float mn = c[0];
        for (int l = 1; l < NLAYER; l++) if (c[l] < mn) { mn = c[l]; idx = l; }
        idx += 1;
        float acc = 0.0f;
        for (int l = 0; l < idx; l++) {
            acc += c[l];
            float p = halts[tid * NLAYER + l];
            p = fminf(fmaxf(p, 1e-7f), 1.0f - 1e-7f);
            float hl = (l == idx - 1) ? 0.0f : 1.0f;
            acc += -(hl * logf(p) + (1.0f - hl) * log1pf(-p));
        }
        bl[tid] = acc / (float)idx;
    }
    __syncthreads();
    if (tid == 0) {
        float t = 0.0f;
        for (int b = 0; b < BBATCH; b++) t += bl[b];
        out[0] = t * (1.0f / (float)BBATCH);
    }
}

extern "C" void kernel_launch(void* const* d_in, const int* in_sizes, int n_in,
                              void* d_out, int out_size, void* d_ws, size_t ws_size,
                              hipStream_t stream)
{
    const float* x      = (const float*)d_in[0];
    const int*   y      = (const int*)d_in[1];
    const float* pos    = (const float*)d_in[2];
    const float* clstok = (const float*)d_in[3];
    const float* Wp     = (const float*)d_in[4];
    const float* bp     = (const float*)d_in[5];
    const float* Wqkv   = (const float*)d_in[6];
    const float* Wo     = (const float*)d_in[7];
    const float* bo     = (const float*)d_in[8];
    const float* ln1g   = (const float*)d_in[9];
    const float* ln1b   = (const float*)d_in[10];
    const float* ln2g   = (const float*)d_in[11];
    const float* ln2b   = (const float*)d_in[12];
    const float* W1     = (const float*)d_in[13];
    const float* b1     = (const float*)d_in[14];
    const float* W2     = (const float*)d_in[15];
    const float* b2     = (const float*)d_in[16];
    const float* lnhg   = (const float*)d_in[17];
    const float* lnhb   = (const float*)d_in[18];
    const float* Wh1    = (const float*)d_in[19];
    const float* bh1    = (const float*)d_in[20];
    const float* Wh2    = (const float*)d_in[21];
    const float* bh2    = (const float*)d_in[22];
    const float* lncg   = (const float*)d_in[23];
    const float* lncb   = (const float*)d_in[24];
    const float* Wc1    = (const float*)d_in[25];
    const float* bc1    = (const float*)d_in[26];
    const float* Wc2    = (const float*)d_in[27];
    const float* bc2    = (const float*)d_in[28];

    // ---- workspace layout ----
    float* U      = (float*)d_ws;                         // MTOK*512 f32
    float* CLS    = U + (size_t)MTOK * DDIM;              // 320*512
    float* LOGITS = CLS + (size_t)BBATCH * NLAYER * DDIM; // 3200
    float* HSC    = LOGITS + BBATCH * NLAYER * NCLASS;    // 10*MTOK
    float* HALTS  = HSC + (size_t)NLAYER * MTOK;          // 320
    u16* QKVb = (u16*)(HALTS + BBATCH * NLAYER + 32);     // QKVROWS*1536 (aliases EMB)
    float* EMB = (float*)QKVb;                            // MPATCH*512 f32 (pre-loop only)
    u16* LNB1 = QKVb + (size_t)QKVROWS * 1536;            // MPAD*512
    u16* LNB2 = LNB1 + (size_t)MPAD * DDIM;               // MPAD*512
    u16* LNBh = LNB2 + (size_t)MPAD * DDIM;               // MPAD*512
    u16* HB   = LNBh + (size_t)MPAD * DDIM;               // MPAD*2048 (aliases XP)
    u16* XP   = HB;                                       // MPATCH*768 (pre-loop only)
    u16* CLNB = HB + (size_t)MPAD * MLPDIM;               // 384*512
    u16* wWp  = CLNB + 384 * DDIM;                        // contiguous bf16 weights
    u16* wWqkv= wWp   + 512 * 768;
    u16* wWo  = wWqkv + 1536 * 512;
    u16* wW1  = wWo   + 512 * 512;
    u16* wW2  = wW1   + 2048 * 512;
    u16* wWh1 = wW2   + 512 * 2048;
    u16* wWc1 = wWh1  + 2048 * 512;

    dim3 blk(256);
    const u16* dummyA = LNB1; const float* dummyF = bh2;

    // ---- setup ----
    convert7_kernel<<<dim3(1024), blk, 0, stream>>>(Wp, Wqkv, Wo, W1, W2, Wh1, Wc1, wWp);
    hipMemsetAsync(HSC, 0, (size_t)NLAYER * MTOK * sizeof(float), stream);
    patch_kernel<<<dim3(2048), blk, 0, stream>>>(x, XP);
    mgemm_kernel<0,1,0,0,0><<<dim3(4, 49), blk, 0, stream>>>(
        XP, wWp, bp, nullptr, (void*)EMB, MPATCH, DDIM, PDIM, PDIM, 49);
    assemble_kernel<<<dim3(2048), blk, 0, stream>>>(EMB, clstok, pos, U);
    ln_dual_kernel<<<dim3(256), blk, 0, stream>>>(U, ln1g, ln1b, lnhg, lnhb, LNB1, LNBh, MTOK);

    for (int l = 0; l < NLAYER; l++) {
        // 1: QKV GEMM || halt GEMM (layer l-1)
        if (l == 0) {
            gemm256_kernel<0,0><<<dim3(300), dim3(512), 0, stream>>>(
                300, 12, 12, LNB1, wWqkv, nullptr, (void*)QKVb, 1536,
                LNB1, wWqkv, nullptr, nullptr, (void*)QKVb, 1536, MTOK);
        } else {
            gemm256_kernel<0,1><<<dim3(700), dim3(512), 0, stream>>>(
                300, 12, 16, LNB1, wWqkv, nullptr, (void*)QKVb, 1536,
                LNBh, wWh1, bh1, Wh2, (void*)(HSC + (size_t)(l-1) * MTOK), 2048, MTOK);
        }
        // 2: attn || halt-mean (layer l-1)
        if (l == 0) {
            attn_hm_kernel<0><<<dim3(512), blk, 0, stream>>>(
                QKVb, LNB1, nullptr, dummyF, U, HALTS, CLS, 0);
        } else {
            attn_hm_kernel<1><<<dim3(544), blk, 0, stream>>>(
                QKVb, LNB1, HSC + (size_t)(l-1) * MTOK, bh2, U, HALTS, CLS, l - 1);
        }
        // 3: Wo + residual -> U
        mgemm_kernel<0,1,1,0,0><<<dim3(4, 50), blk, 0, stream>>>(
            LNB1, wWo, bo, U, (void*)U, MTOK, DDIM, DDIM, DDIM, 50);
        // 4: ln2
        ln_one_kernel<<<dim3(256), blk, 0, stream>>>(U, ln2g, ln2b, LNB2, MTOK);
        // 5: W1 (gelu) -> HB
        gemm256_kernel<2,2><<<dim3(400), dim3(512), 0, stream>>>(
            400, 16, 16, LNB2, wW1, b1, (void*)HB, 2048,
            LNB2, wW1, b1, nullptr, (void*)HB, 2048, MTOK);
        // 6: W2 split-K2, atomic += into U (bias on ks==0)
        mgemm_kernel<0,1,0,0,1><<<dim3(4, 100), blk, 0, stream>>>(
            HB, wW2, b2, nullptr, (void*)U, MTOK, DDIM, MLPDIM, 1024, 50);
        // 7: fused ln1 + lnh of the new U
        ln_dual_kernel<<<dim3(256), blk, 0, stream>>>(
            U, ln1g, ln1b, lnhg, lnhb, LNB1, LNBh, MTOK);
    }

    // final halt GEMM (layer 9) + halt-mean
    gemm256_kernel<1,1><<<dim3(400), dim3(512), 0, stream>>>(
        400, 16, 16, LNBh, wWh1, bh1, (void*)(HSC + (size_t)9 * MTOK), 2048,
        LNBh, wWh1, bh1, Wh2, (void*)(HSC + (size_t)9 * MTOK), 2048, MTOK);
    haltmean_kernel<<<dim3(BBATCH), dim3(64), 0, stream>>>(
        HSC + (size_t)9 * MTOK, bh2, U, HALTS, CLS, 9);

    // head
    ln_one_kernel<<<dim3(80), blk, 0, stream>>>(CLS, lncg, lncb, CLNB, BBATCH * NLAYER);
    mgemm_kernel<1,1,0,1,0><<<dim3(16, 3), blk, 0, stream>>>(
        CLNB, wWc1, bc1, nullptr, (void*)HB, BBATCH * NLAYER, MLPDIM, DDIM, DDIM, 3);
    head_logits_kernel<<<dim3(80), blk, 0, stream>>>(HB, Wc2, bc2, LOGITS);
    celoss_kernel<<<dim3(1), blk, 0, stream>>>(LOGITS, y, HALTS, (float*)d_out);
}